// Round 1
// baseline (2699.550 us; speedup 1.0000x reference)
//
#include <hip/hip_runtime.h>
#include <math.h>

#define N_NODES 50000
#define F_IN    256
#define H1      4
#define C1      32
#define HC      128
#define C2      128
#define QDIM    768
#define NE      800000
#define ET      (NE + N_NODES)

// ---------------- helpers ----------------

__device__ __forceinline__ void atomicMaxFloat(float* addr, float val) {
    if (val >= 0.f)
        atomicMax(reinterpret_cast<int*>(addr), __float_as_int(val));
    else
        atomicMin(reinterpret_cast<unsigned int*>(addr), __float_as_uint(val));
}

__device__ __forceinline__ void edge_sd(const int* __restrict__ ei, int e, int& s, int& d) {
    if (e < NE) { s = ei[e]; d = ei[NE + e]; }
    else        { s = e - NE; d = e - NE; }      // self loops appended
}

// ---------------- init ----------------

// m1[N*4], den1[N*4], m2[N], den2[N], scal[3] = {qdot, gmax, gsum}
__global__ void init_kernel(float* m1, float* den1, float* m2, float* den2, float* scal) {
    int i = blockIdx.x * blockDim.x + threadIdx.x;
    if (i < N_NODES * H1) { m1[i] = -INFINITY; den1[i] = 0.f; }
    if (i < N_NODES)      { m2[i] = -INFINITY; den2[i] = 0.f; }
    if (i == 0)           { scal[1] = -INFINITY; scal[2] = 0.f; }
}

// qdot = q . Wq[128:] + bq
__global__ void qdot_kernel(const float* __restrict__ q, const float* __restrict__ Wq,
                            const float* __restrict__ bq, float* scal) {
    __shared__ float sm[256];
    float acc = 0.f;
    for (int i = threadIdx.x; i < QDIM; i += 256) acc += q[i] * Wq[C2 + i];
    sm[threadIdx.x] = acc;
    __syncthreads();
    for (int o = 128; o > 0; o >>= 1) {
        if (threadIdx.x < o) sm[threadIdx.x] += sm[threadIdx.x + o];
        __syncthreads();
    }
    if (threadIdx.x == 0) scal[0] = sm[0] + bq[0];
}

// ---------------- GEMM (fp32, row-major, C = A[M,K] @ B[K,Nc]) ----------------

#define BM 64
#define BN 64
#define BKK 16

__global__ __launch_bounds__(256) void gemm_f32(const float* __restrict__ A,
                                                const float* __restrict__ B,
                                                float* __restrict__ C,
                                                int M, int K, int Nc) {
    __shared__ float As[BKK][BM + 1];
    __shared__ float Bs[BKK][BN];
    const int t  = threadIdx.x;
    const int tx = t & 15, ty = t >> 4;
    const int row0 = blockIdx.y * BM;
    const int col0 = blockIdx.x * BN;
    float acc[4][4] = {};
    for (int k0 = 0; k0 < K; k0 += BKK) {
#pragma unroll
        for (int i = 0; i < 4; i++) {
            int e = t + i * 256;
            int m = e >> 4, k = e & 15;
            int r = row0 + m;
            As[k][m] = (r < M) ? A[(long)r * K + k0 + k] : 0.f;
        }
#pragma unroll
        for (int i = 0; i < 4; i++) {
            int e = t + i * 256;
            int k = e >> 6, n = e & 63;
            Bs[k][n] = B[(long)(k0 + k) * Nc + col0 + n];
        }
        __syncthreads();
#pragma unroll
        for (int k = 0; k < BKK; k++) {
            float a[4], b[4];
#pragma unroll
            for (int i = 0; i < 4; i++) a[i] = As[k][ty * 4 + i];
#pragma unroll
            for (int j = 0; j < 4; j++) b[j] = Bs[k][tx * 4 + j];
#pragma unroll
            for (int i = 0; i < 4; i++)
#pragma unroll
                for (int j = 0; j < 4; j++) acc[i][j] += a[i] * b[j];
        }
        __syncthreads();
    }
#pragma unroll
    for (int i = 0; i < 4; i++) {
        int r = row0 + ty * 4 + i;
        if (r < M) {
#pragma unroll
            for (int j = 0; j < 4; j++)
                C[(long)r * Nc + col0 + tx * 4 + j] = acc[i][j];
        }
    }
}

// ---------------- per-node alpha (dot with a_src/a_dst) ----------------

// one thread per (n,h); NH = N*H, C channels per head, row stride HC=128
__global__ void alpha_kernel(const float* __restrict__ xw,
                             const float* __restrict__ a_src,
                             const float* __restrict__ a_dst,
                             float* __restrict__ as_, float* __restrict__ ad_,
                             int NH, int H, int C) {
    int i = blockIdx.x * blockDim.x + threadIdx.x;
    if (i >= NH) return;
    int n = i / H, h = i - n * H;
    const float* row = xw + (long)n * HC + h * C;
    const float* vs  = a_src + h * C;
    const float* vd  = a_dst + h * C;
    float s = 0.f, d = 0.f;
    for (int k = 0; k < C; k++) {
        float v = row[k];
        s += v * vs[k];
        d += v * vd[k];
    }
    as_[i] = s;
    ad_[i] = d;
}

// ---------------- edge passes ----------------

// pass 1: e = leaky_relu(as[src]+ad[dst]); store; atomicMax per dst
__global__ void edge_max_kernel(const int* __restrict__ ei,
                                const float* __restrict__ as_, const float* __restrict__ ad_,
                                float* __restrict__ ebuf, float* __restrict__ m, int H) {
    int e = blockIdx.x * blockDim.x + threadIdx.x;
    if (e >= ET) return;
    int s, d;
    edge_sd(ei, e, s, d);
    for (int h = 0; h < H; h++) {
        float v = as_[s * H + h] + ad_[d * H + h];
        v = (v > 0.f) ? v : 0.2f * v;
        ebuf[(long)e * H + h] = v;
        atomicMaxFloat(&m[d * H + h], v);
    }
}

// pass 2: v = exp(e - m[dst]); store; atomicAdd denom
__global__ void edge_expsum_kernel(const int* __restrict__ ei,
                                   float* __restrict__ ebuf,
                                   const float* __restrict__ m, float* __restrict__ den, int H) {
    int e = blockIdx.x * blockDim.x + threadIdx.x;
    if (e >= ET) return;
    int s, d;
    edge_sd(ei, e, s, d);
    for (int h = 0; h < H; h++) {
        float v = __expf(ebuf[(long)e * H + h] - m[d * H + h]);
        ebuf[(long)e * H + h] = v;
        unsafeAtomicAdd(&den[d * H + h], v);
    }
}

// pass 3: out[dst] += (e/denom[dst]) * xw[src]; one wave (64 lanes) per edge,
// 2 channels per lane (HC=128). c_shift: log2(C) to get head from channel.
__global__ __launch_bounds__(256) void edge_msg_kernel(const int* __restrict__ ei,
                                                       const float* __restrict__ ebuf,
                                                       const float* __restrict__ den,
                                                       const float* __restrict__ xw,
                                                       float* __restrict__ out,
                                                       int H, int c_shift) {
    int wid  = (blockIdx.x * blockDim.x + threadIdx.x) >> 6;   // edge id
    int lane = threadIdx.x & 63;
    if (wid >= ET) return;
    int s, d;
    edge_sd(ei, wid, s, d);
    int c = lane * 2;
    int h = c >> c_shift;
    float alpha = ebuf[(long)wid * H + h] / (den[d * H + h] + 1e-16f);
    const float2 v = *reinterpret_cast<const float2*>(xw + (long)s * HC + c);
    unsafeAtomicAdd(&out[(long)d * HC + c],     alpha * v.x);
    unsafeAtomicAdd(&out[(long)d * HC + c + 1], alpha * v.y);
}

// ---------------- elementwise ----------------

// x = elu(x + bias), in place over N*128
__global__ void elu_bias_kernel(float* __restrict__ x, const float* __restrict__ bias) {
    int i = blockIdx.x * blockDim.x + threadIdx.x;
    if (i >= N_NODES * HC) return;
    float v = x[i] + bias[i & (HC - 1)];
    x[i] = (v > 0.f) ? v : (__expf(v) - 1.f);
    }

// ---------------- final stage ----------------

// wave per node: ents = elu(out2 + b2) in place; logits = ents.Wq[:128] + qdot + mask
__global__ __launch_bounds__(256) void ents_logits_kernel(float* __restrict__ ents,
                                                          const float* __restrict__ b2,
                                                          const float* __restrict__ Wq,
                                                          const int* __restrict__ qmask,
                                                          const float* __restrict__ scal,
                                                          float* __restrict__ logits,
                                                          float* gmax) {
    int wid  = (blockIdx.x * blockDim.x + threadIdx.x) >> 6;   // node
    int lane = threadIdx.x & 63;
    if (wid >= N_NODES) return;
    int c = lane * 2;
    float2 v = *reinterpret_cast<float2*>(ents + (long)wid * HC + c);
    float x0 = v.x + b2[c], x1 = v.y + b2[c + 1];
    x0 = (x0 > 0.f) ? x0 : (__expf(x0) - 1.f);
    x1 = (x1 > 0.f) ? x1 : (__expf(x1) - 1.f);
    float2 w;
    w.x = x0; w.y = x1;
    *reinterpret_cast<float2*>(ents + (long)wid * HC + c) = w;
    float acc = x0 * Wq[c] + x1 * Wq[c + 1];
#pragma unroll
    for (int o = 32; o > 0; o >>= 1) acc += __shfl_down(acc, o);
    if (lane == 0) {
        float lg = acc + scal[0] + ((float)qmask[wid] - 1.f) * 1e9f;
        logits[wid] = lg;
        atomicMaxFloat(gmax, lg);
    }
}

__global__ void exp_kernel(float* __restrict__ logits, const float* __restrict__ scal,
                           float* gsum) {
    int n = blockIdx.x * blockDim.x + threadIdx.x;
    if (n >= N_NODES) return;
    float ex = __expf(logits[n] - scal[1]);
    logits[n] = ex;
    unsafeAtomicAdd(gsum, ex);
}

__global__ void attn_kernel(const float* __restrict__ logits, const float* __restrict__ scal,
                            float* __restrict__ attn_out) {
    int n = blockIdx.x * blockDim.x + threadIdx.x;
    if (n >= N_NODES) return;
    attn_out[n] = logits[n] / scal[2];
}

// pooled[c] = sum_n attn[n]*ents[n*128+c]; 128 threads/block, block-partial + atomic
__global__ __launch_bounds__(128) void pooled_kernel(const float* __restrict__ ents,
                                                     const float* __restrict__ attn,
                                                     float* __restrict__ pooled) {
    int c = threadIdx.x;
    float acc = 0.f;
    for (int n = blockIdx.x; n < N_NODES; n += gridDim.x)
        acc += attn[n] * ents[(long)n * HC + c];
    unsafeAtomicAdd(&pooled[c], acc);
}

// ---------------- launch ----------------

extern "C" void kernel_launch(void* const* d_in, const int* in_sizes, int n_in,
                              void* d_out, int out_size, void* d_ws, size_t ws_size,
                              hipStream_t stream) {
    const float* x     = (const float*)d_in[0];
    const int*   ei    = (const int*)d_in[1];
    const float* q     = (const float*)d_in[2];
    const int*   qmask = (const int*)d_in[3];
    // d_in[4] place_entity_mask: unused by reference
    const float* W1    = (const float*)d_in[5];
    const float* asrc1 = (const float*)d_in[6];
    const float* adst1 = (const float*)d_in[7];
    const float* b1    = (const float*)d_in[8];
    const float* W2    = (const float*)d_in[9];
    const float* asrc2 = (const float*)d_in[10];
    const float* adst2 = (const float*)d_in[11];
    const float* b2    = (const float*)d_in[12];
    const float* Wq    = (const float*)d_in[13];
    const float* bq    = (const float*)d_in[14];

    float* out   = (float*)d_out;
    float* pooled = out;                        // [128]
    float* ents   = out + HC;                   // [N,128]
    float* attn   = out + HC + (long)N_NODES * HC;  // [N]

    // workspace layout
    float* ws   = (float*)d_ws;
    float* xw   = ws;                           // N*128 (xw1, later xw2)
    float* ebuf = xw + (long)N_NODES * HC;      // ET*4 (layer1), ET (layer2)
    float* as1  = ebuf + (long)ET * H1;         // N*4
    float* ad1  = as1 + N_NODES * H1;
    float* m1   = ad1 + N_NODES * H1;
    float* den1 = m1 + N_NODES * H1;
    float* as2  = den1 + N_NODES * H1;          // N
    float* ad2  = as2 + N_NODES;
    float* m2   = ad2 + N_NODES;
    float* den2 = m2 + N_NODES;
    float* logits = den2 + N_NODES;             // N
    float* scal   = logits + N_NODES;           // 3

    const int TB = 256;
    const int g_nh1  = (N_NODES * H1 + TB - 1) / TB;       // 782
    const int g_n    = (N_NODES + TB - 1) / TB;            // 196
    const int g_et   = (ET + TB - 1) / TB;                 // 3321
    const int g_etw  = (ET + 3) / 4;                        // waves: 4/block
    const int g_elu  = (N_NODES * HC + TB - 1) / TB;       // 25000
    const int g_nw   = (N_NODES + 3) / 4;                   // node-waves: 4/block
    dim3 gemm_grid(HC / BN, (N_NODES + BM - 1) / BM);      // (2, 782)

    // zero pooled + ents(=out1 accumulator)
    hipMemsetAsync(d_out, 0, (size_t)(HC + (long)N_NODES * HC) * sizeof(float), stream);
    init_kernel<<<g_nh1, TB, 0, stream>>>(m1, den1, m2, den2, scal);
    qdot_kernel<<<1, TB, 0, stream>>>(q, Wq, bq, scal);

    // ---- layer 1 ----
    gemm_f32<<<gemm_grid, TB, 0, stream>>>(x, W1, xw, N_NODES, F_IN, HC);
    alpha_kernel<<<g_nh1, TB, 0, stream>>>(xw, asrc1, adst1, as1, ad1, N_NODES * H1, H1, C1);
    edge_max_kernel<<<g_et, TB, 0, stream>>>(ei, as1, ad1, ebuf, m1, H1);
    edge_expsum_kernel<<<g_et, TB, 0, stream>>>(ei, ebuf, m1, den1, H1);
    edge_msg_kernel<<<g_etw, TB, 0, stream>>>(ei, ebuf, den1, xw, ents, H1, 5 /*log2(32)*/);
    elu_bias_kernel<<<g_elu, TB, 0, stream>>>(ents, b1);   // ents now = x1

    // ---- layer 2 ----
    gemm_f32<<<gemm_grid, TB, 0, stream>>>(ents, W2, xw, N_NODES, HC, HC);
    alpha_kernel<<<g_n, TB, 0, stream>>>(xw, asrc2, adst2, as2, ad2, N_NODES, 1, C2);
    // re-zero ents region for layer-2 accumulation
    hipMemsetAsync(ents, 0, (size_t)N_NODES * HC * sizeof(float), stream);
    edge_max_kernel<<<g_et, TB, 0, stream>>>(ei, as2, ad2, ebuf, m2, 1);
    edge_expsum_kernel<<<g_et, TB, 0, stream>>>(ei, ebuf, m2, den2, 1);
    edge_msg_kernel<<<g_etw, TB, 0, stream>>>(ei, ebuf, den2, xw, ents, 1, 7 /*log2(128)*/);

    // ---- final ----
    ents_logits_kernel<<<g_nw, TB, 0, stream>>>(ents, b2, Wq, qmask, scal, logits, &scal[1]);
    exp_kernel<<<g_n, TB, 0, stream>>>(logits, scal, &scal[2]);
    attn_kernel<<<g_n, TB, 0, stream>>>(logits, scal, attn);
    pooled_kernel<<<512, 128, 0, stream>>>(ents, attn, pooled);
}

// Round 3
// 1138.499 us; speedup vs baseline: 2.3711x; 2.3711x over previous
//
#include <hip/hip_runtime.h>
#include <math.h>

#define N_NODES 50000
#define F_IN    256
#define H1      4
#define C1      32
#define HC      128
#define C2      128
#define QDIM    768
#define NE      800000
#define NB_SCAN 196          // ceil(50000/256)

// ---------------- helpers ----------------

__device__ __forceinline__ void atomicMaxFloat(float* addr, float val) {
    if (val >= 0.f)
        atomicMax(reinterpret_cast<int*>(addr), __float_as_int(val));
    else
        atomicMin(reinterpret_cast<unsigned int*>(addr), __float_as_uint(val));
}

// ---------------- init ----------------

__global__ void init_scal_kernel(float* scal) {
    scal[1] = -INFINITY;   // global logit max
    scal[2] = 0.f;         // global exp sum
}

// qdot = q . Wq[128:] + bq
__global__ void qdot_kernel(const float* __restrict__ q, const float* __restrict__ Wq,
                            const float* __restrict__ bq, float* scal) {
    __shared__ float sm[256];
    float acc = 0.f;
    for (int i = threadIdx.x; i < QDIM; i += 256) acc += q[i] * Wq[C2 + i];
    sm[threadIdx.x] = acc;
    __syncthreads();
    for (int o = 128; o > 0; o >>= 1) {
        if (threadIdx.x < o) sm[threadIdx.x] += sm[threadIdx.x + o];
        __syncthreads();
    }
    if (threadIdx.x == 0) scal[0] = sm[0] + bq[0];
}

// ---------------- CSR build (counting sort by dst) ----------------

__global__ void hist_kernel(const int* __restrict__ ei, int* __restrict__ deg) {
    int e = blockIdx.x * blockDim.x + threadIdx.x;
    if (e >= NE) return;
    atomicAdd(&deg[ei[NE + e]], 1);
}

__global__ void scan1_kernel(const int* __restrict__ deg, int* __restrict__ incl,
                             int* __restrict__ bsum) {
    __shared__ int sm[256];
    int i = blockIdx.x * 256 + threadIdx.x;
    int v = (i < N_NODES) ? deg[i] : 0;
    sm[threadIdx.x] = v;
    __syncthreads();
    for (int o = 1; o < 256; o <<= 1) {
        int t = (threadIdx.x >= o) ? sm[threadIdx.x - o] : 0;
        __syncthreads();
        sm[threadIdx.x] += t;
        __syncthreads();
    }
    if (i < N_NODES) incl[i] = sm[threadIdx.x];
    if (threadIdx.x == 255) bsum[blockIdx.x] = sm[255];
}

__global__ void scan2_kernel(int* __restrict__ bsum) {
    __shared__ int sm[256];
    int v = (threadIdx.x < NB_SCAN) ? bsum[threadIdx.x] : 0;
    sm[threadIdx.x] = v;
    __syncthreads();
    for (int o = 1; o < 256; o <<= 1) {
        int t = (threadIdx.x >= o) ? sm[threadIdx.x - o] : 0;
        __syncthreads();
        sm[threadIdx.x] += t;
        __syncthreads();
    }
    if (threadIdx.x < NB_SCAN) bsum[threadIdx.x] = sm[threadIdx.x] - v;
}

__global__ void scan3_kernel(const int* __restrict__ deg, const int* __restrict__ incl,
                             const int* __restrict__ bsum, int* __restrict__ rowptr,
                             int* __restrict__ cursor) {
    int i = blockIdx.x * 256 + threadIdx.x;
    if (i >= N_NODES) return;
    int excl = incl[i] - deg[i] + bsum[i >> 8];
    rowptr[i] = excl;
    cursor[i] = excl;
    if (i == N_NODES - 1) rowptr[N_NODES] = excl + deg[i];
}

__global__ void scatter_kernel(const int* __restrict__ ei, int* __restrict__ cursor,
                               int* __restrict__ colsrc) {
    int e = blockIdx.x * blockDim.x + threadIdx.x;
    if (e >= NE) return;
    int s = ei[e], d = ei[NE + e];
    int pos = atomicAdd(&cursor[d], 1);
    colsrc[pos] = s;
}

// ---------------- GEMM (fp32, row-major, C = A[M,K] @ B[K,Nc]) ----------------

#define BM 64
#define BN 64
#define BKK 16

__global__ __launch_bounds__(256) void gemm_f32(const float* __restrict__ A,
                                                const float* __restrict__ B,
                                                float* __restrict__ C,
                                                int M, int K, int Nc) {
    __shared__ float As[BKK][BM + 1];
    __shared__ float Bs[BKK][BN];
    const int t  = threadIdx.x;
    const int tx = t & 15, ty = t >> 4;
    const int row0 = blockIdx.y * BM;
    const int col0 = blockIdx.x * BN;
    float acc[4][4] = {};
    for (int k0 = 0; k0 < K; k0 += BKK) {
#pragma unroll
        for (int i = 0; i < 4; i++) {
            int e = t + i * 256;
            int m = e >> 4, k = e & 15;
            int r = row0 + m;
            As[k][m] = (r < M) ? A[(long)r * K + k0 + k] : 0.f;
        }
#pragma unroll
        for (int i = 0; i < 4; i++) {
            int e = t + i * 256;
            int k = e >> 6, n = e & 63;
            Bs[k][n] = B[(long)(k0 + k) * Nc + col0 + n];
        }
        __syncthreads();
#pragma unroll
        for (int k = 0; k < BKK; k++) {
            float a[4], b[4];
#pragma unroll
            for (int i = 0; i < 4; i++) a[i] = As[k][ty * 4 + i];
#pragma unroll
            for (int j = 0; j < 4; j++) b[j] = Bs[k][tx * 4 + j];
#pragma unroll
            for (int i = 0; i < 4; i++)
#pragma unroll
                for (int j = 0; j < 4; j++) acc[i][j] += a[i] * b[j];
        }
        __syncthreads();
    }
#pragma unroll
    for (int i = 0; i < 4; i++) {
        int r = row0 + ty * 4 + i;
        if (r < M) {
#pragma unroll
            for (int j = 0; j < 4; j++)
                C[(long)r * Nc + col0 + tx * 4 + j] = acc[i][j];
        }
    }
}

// ---------------- per-node alpha (dot with a_src/a_dst) ----------------

__global__ void alpha_kernel(const float* __restrict__ xw,
                             const float* __restrict__ a_src,
                             const float* __restrict__ a_dst,
                             float* __restrict__ as_, float* __restrict__ ad_,
                             int NH, int H, int C) {
    int i = blockIdx.x * blockDim.x + threadIdx.x;
    if (i >= NH) return;
    int n = i / H, h = i - n * H;
    const float* row = xw + (long)n * HC + h * C;
    const float* vs  = a_src + h * C;
    const float* vd  = a_dst + h * C;
    float s = 0.f, d = 0.f;
    for (int k = 0; k < C; k++) {
        float v = row[k];
        s += v * vs[k];
        d += v * vd[k];
    }
    as_[i] = s;
    ad_[i] = d;
}

// ---------------- fused GAT aggregate: one wave per dst node ----------------
// Lane decomposition (fixes round-2 head-mixing bug): CHUNK = 64/H edges per
// iteration; lane l handles edge-slot (l % CHUNK) for head (l / CHUNK).
// Lane l's output channels 2l,2l+1 belong to head (2l)/(2C) == l/CHUNK, so
// softmax state (m, den) is a per-lane scalar for exactly the right head.
// Reductions are CHUNK-lane-group shfl_xor; gather fetches edge j's alpha
// from lane (group_base + j) — the lane that computed (edge j, my head).

template<int H>
__global__ __launch_bounds__(256) void gat_agg_kernel(const int* __restrict__ rowptr,
                                                      const int* __restrict__ colsrc,
                                                      const float* __restrict__ as_,
                                                      const float* __restrict__ ad_,
                                                      const float* __restrict__ xw,
                                                      const float* __restrict__ bias,
                                                      float* __restrict__ outbuf,
                                                      int fuse_elu) {
    constexpr int CHUNK = 64 / H;
    int n    = (blockIdx.x * blockDim.x + threadIdx.x) >> 6;
    int lane = threadIdx.x & 63;
    if (n >= N_NODES) return;
    const int c     = lane * 2;
    const int h_my  = lane / CHUNK;
    const int eslot = lane & (CHUNK - 1);
    const int gbase = lane - eslot;

    // self-loop seeds the online softmax: m = e_self, den = exp(0) = 1, acc = xw[n]
    const float adn = ad_[n * H + h_my];
    float m;
    {
        float v = as_[n * H + h_my] + adn;
        m = (v > 0.f) ? v : 0.2f * v;
    }
    float den = 1.f;
    float2 acc = *reinterpret_cast<const float2*>(xw + (long)n * HC + c);

    const int rbeg = rowptr[n], rend = rowptr[n + 1];
    for (int base = rbeg; base < rend; base += CHUNK) {
        int idx = base + eslot;
        int s   = (idx < rend) ? colsrc[idx] : -1;
        float ev;
        if (s >= 0) {
            float v = as_[(long)s * H + h_my] + adn;
            ev = (v > 0.f) ? v : 0.2f * v;
        } else {
            ev = -INFINITY;
        }
        // group max over CHUNK lanes, merge with running max, rescale
        float cm = ev;
#pragma unroll
        for (int o = CHUNK / 2; o > 0; o >>= 1) cm = fmaxf(cm, __shfl_xor(cm, o));
        float nm = fmaxf(m, cm);
        float sc = __expf(m - nm);
        den *= sc;
        acc.x *= sc; acc.y *= sc;
        m = nm;
        // exp values + denom update
        float e_ = (s >= 0) ? __expf(ev - nm) : 0.f;
        float ssum = e_;
#pragma unroll
        for (int o = CHUNK / 2; o > 0; o >>= 1) ssum += __shfl_xor(ssum, o);
        den += ssum;
        // gather: serial over chunk edges, lanes over channels
        int cnt = min(CHUNK, rend - base);
        for (int j = 0; j < cnt; j++) {
            int   sj = __shfl(s, j);            // same for all head groups
            float aj = __shfl(e_, gbase + j);   // edge j's exp for MY head
            const float2 v = *reinterpret_cast<const float2*>(xw + (long)sj * HC + c);
            acc.x += aj * v.x;
            acc.y += aj * v.y;
        }
    }

    float inv = 1.f / (den + 1e-16f);
    float x0 = acc.x * inv, x1 = acc.y * inv;
    if (fuse_elu) {
        x0 += bias[c]; x1 += bias[c + 1];
        x0 = (x0 > 0.f) ? x0 : (__expf(x0) - 1.f);
        x1 = (x1 > 0.f) ? x1 : (__expf(x1) - 1.f);
    }
    float2 o; o.x = x0; o.y = x1;
    *reinterpret_cast<float2*>(outbuf + (long)n * HC + c) = o;
}

// ---------------- final stage ----------------

__global__ __launch_bounds__(256) void ents_logits_kernel(float* __restrict__ ents,
                                                          const float* __restrict__ b2,
                                                          const float* __restrict__ Wq,
                                                          const int* __restrict__ qmask,
                                                          const float* __restrict__ scal,
                                                          float* __restrict__ logits,
                                                          float* gmax) {
    int wid  = (blockIdx.x * blockDim.x + threadIdx.x) >> 6;
    int lane = threadIdx.x & 63;
    if (wid >= N_NODES) return;
    int c = lane * 2;
    float2 v = *reinterpret_cast<float2*>(ents + (long)wid * HC + c);
    float x0 = v.x + b2[c], x1 = v.y + b2[c + 1];
    x0 = (x0 > 0.f) ? x0 : (__expf(x0) - 1.f);
    x1 = (x1 > 0.f) ? x1 : (__expf(x1) - 1.f);
    float2 w; w.x = x0; w.y = x1;
    *reinterpret_cast<float2*>(ents + (long)wid * HC + c) = w;
    float acc = x0 * Wq[c] + x1 * Wq[c + 1];
#pragma unroll
    for (int o = 32; o > 0; o >>= 1) acc += __shfl_down(acc, o);
    if (lane == 0) {
        float lg = acc + scal[0] + ((float)qmask[wid] - 1.f) * 1e9f;
        logits[wid] = lg;
        atomicMaxFloat(gmax, lg);
    }
}

__global__ void exp_kernel(float* __restrict__ logits, const float* __restrict__ scal,
                           float* gsum) {
    int n = blockIdx.x * blockDim.x + threadIdx.x;
    if (n >= N_NODES) return;
    float ex = __expf(logits[n] - scal[1]);
    logits[n] = ex;
    unsafeAtomicAdd(gsum, ex);
}

__global__ void attn_kernel(const float* __restrict__ logits, const float* __restrict__ scal,
                            float* __restrict__ attn_out) {
    int n = blockIdx.x * blockDim.x + threadIdx.x;
    if (n >= N_NODES) return;
    attn_out[n] = logits[n] / scal[2];
}

__global__ __launch_bounds__(128) void pooled_kernel(const float* __restrict__ ents,
                                                     const float* __restrict__ attn,
                                                     float* __restrict__ pooled) {
    int c = threadIdx.x;
    float acc = 0.f;
    for (int n = blockIdx.x; n < N_NODES; n += gridDim.x)
        acc += attn[n] * ents[(long)n * HC + c];
    unsafeAtomicAdd(&pooled[c], acc);
}

// ---------------- launch ----------------

extern "C" void kernel_launch(void* const* d_in, const int* in_sizes, int n_in,
                              void* d_out, int out_size, void* d_ws, size_t ws_size,
                              hipStream_t stream) {
    const float* x     = (const float*)d_in[0];
    const int*   ei    = (const int*)d_in[1];
    const float* q     = (const float*)d_in[2];
    const int*   qmask = (const int*)d_in[3];
    const float* W1    = (const float*)d_in[5];
    const float* asrc1 = (const float*)d_in[6];
    const float* adst1 = (const float*)d_in[7];
    const float* b1    = (const float*)d_in[8];
    const float* W2    = (const float*)d_in[9];
    const float* asrc2 = (const float*)d_in[10];
    const float* adst2 = (const float*)d_in[11];
    const float* b2    = (const float*)d_in[12];
    const float* Wq    = (const float*)d_in[13];
    const float* bq    = (const float*)d_in[14];

    float* out    = (float*)d_out;
    float* pooled = out;                              // [128]
    float* ents   = out + HC;                         // [N,128]
    float* attn   = out + HC + (long)N_NODES * HC;    // [N]

    // workspace layout
    float* ws     = (float*)d_ws;
    float* xw     = ws;                               // N*128
    float* as1    = xw + (long)N_NODES * HC;          // N*4
    float* ad1    = as1 + N_NODES * H1;
    float* as2    = ad1 + N_NODES * H1;               // N
    float* ad2    = as2 + N_NODES;
    float* logits = ad2 + N_NODES;                    // N
    float* scal   = logits + N_NODES;                 // 3
    int*   deg    = (int*)(scal + 4);                 // N
    int*   incl   = deg + N_NODES;                    // N
    int*   bsum   = incl + N_NODES;                   // 256
    int*   rowptr = bsum + 256;                       // N+1
    int*   cursor = rowptr + N_NODES + 1;             // N
    int*   colsrc = cursor + N_NODES;                 // NE

    const int TB = 256;
    const int g_nh1 = (N_NODES * H1 + TB - 1) / TB;   // 782
    const int g_n   = (N_NODES + TB - 1) / TB;        // 196
    const int g_e   = (NE + TB - 1) / TB;             // 3125
    const int g_nw  = (N_NODES + 3) / 4;              // node-waves, 4/block
    dim3 gemm_grid(HC / BN, (N_NODES + BM - 1) / BM); // (2, 782)

    hipMemsetAsync(pooled, 0, HC * sizeof(float), stream);
    hipMemsetAsync(deg, 0, N_NODES * sizeof(int), stream);
    init_scal_kernel<<<1, 1, 0, stream>>>(scal);
    qdot_kernel<<<1, TB, 0, stream>>>(q, Wq, bq, scal);

    // ---- CSR build (dst-sorted) ----
    hist_kernel<<<g_e, TB, 0, stream>>>(ei, deg);
    scan1_kernel<<<NB_SCAN, TB, 0, stream>>>(deg, incl, bsum);
    scan2_kernel<<<1, TB, 0, stream>>>(bsum);
    scan3_kernel<<<NB_SCAN, TB, 0, stream>>>(deg, incl, bsum, rowptr, cursor);
    scatter_kernel<<<g_e, TB, 0, stream>>>(ei, cursor, colsrc);

    // ---- layer 1 ----
    gemm_f32<<<gemm_grid, TB, 0, stream>>>(x, W1, xw, N_NODES, F_IN, HC);
    alpha_kernel<<<g_nh1, TB, 0, stream>>>(xw, asrc1, adst1, as1, ad1, N_NODES * H1, H1, C1);
    gat_agg_kernel<H1><<<g_nw, TB, 0, stream>>>(rowptr, colsrc, as1, ad1, xw, b1, ents, 1);

    // ---- layer 2 ----
    gemm_f32<<<gemm_grid, TB, 0, stream>>>(ents, W2, xw, N_NODES, HC, HC);
    alpha_kernel<<<g_n, TB, 0, stream>>>(xw, asrc2, adst2, as2, ad2, N_NODES, 1, C2);
    gat_agg_kernel<1><<<g_nw, TB, 0, stream>>>(rowptr, colsrc, as2, ad2, xw, b2, ents, 0);

    // ---- final ----
    ents_logits_kernel<<<g_nw, TB, 0, stream>>>(ents, b2, Wq, qmask, scal, logits, &scal[1]);
    exp_kernel<<<g_n, TB, 0, stream>>>(logits, scal, &scal[2]);
    attn_kernel<<<g_n, TB, 0, stream>>>(logits, scal, attn);
    pooled_kernel<<<512, 128, 0, stream>>>(ents, attn, pooled);
}

// Round 8
// 580.379 us; speedup vs baseline: 4.6514x; 1.9616x over previous
//
#include <hip/hip_runtime.h>
#include <math.h>

#define N_NODES 50000
#define F_IN    256
#define H1      4
#define C1      32
#define HC      128
#define C2      128
#define QDIM    768
#define NE      800000
#define NB_SCAN 196          // ceil(50000/256)
#define NB_POOL 512

// ---------------- helpers ----------------

__device__ __forceinline__ void atomicMaxFloat(float* addr, float val) {
    if (val >= 0.f)
        atomicMax(reinterpret_cast<int*>(addr), __float_as_int(val));
    else
        atomicMin(reinterpret_cast<unsigned int*>(addr), __float_as_uint(val));
}

// ---------------- init ----------------

__global__ void init_scal_kernel(float* scal) {
    scal[1] = -INFINITY;   // global logit max
    scal[2] = 0.f;         // global exp sum
}

// qdot = q . Wq[128:] + bq
__global__ void qdot_kernel(const float* __restrict__ q, const float* __restrict__ Wq,
                            const float* __restrict__ bq, float* scal) {
    __shared__ float sm[256];
    float acc = 0.f;
    for (int i = threadIdx.x; i < QDIM; i += 256) acc += q[i] * Wq[C2 + i];
    sm[threadIdx.x] = acc;
    __syncthreads();
    for (int o = 128; o > 0; o >>= 1) {
        if (threadIdx.x < o) sm[threadIdx.x] += sm[threadIdx.x + o];
        __syncthreads();
    }
    if (threadIdx.x == 0) scal[0] = sm[0] + bq[0];
}

// ---------------- CSR build (counting sort by dst) ----------------

__global__ void hist_kernel(const int* __restrict__ ei, int* __restrict__ deg) {
    int e = blockIdx.x * blockDim.x + threadIdx.x;
    if (e >= NE) return;
    atomicAdd(&deg[ei[NE + e]], 1);
}

__global__ void scan1_kernel(const int* __restrict__ deg, int* __restrict__ incl,
                             int* __restrict__ bsum) {
    __shared__ int sm[256];
    int i = blockIdx.x * 256 + threadIdx.x;
    int v = (i < N_NODES) ? deg[i] : 0;
    sm[threadIdx.x] = v;
    __syncthreads();
    for (int o = 1; o < 256; o <<= 1) {
        int t = (threadIdx.x >= o) ? sm[threadIdx.x - o] : 0;
        __syncthreads();
        sm[threadIdx.x] += t;
        __syncthreads();
    }
    if (i < N_NODES) incl[i] = sm[threadIdx.x];
    if (threadIdx.x == 255) bsum[blockIdx.x] = sm[255];
}

__global__ void scan2_kernel(int* __restrict__ bsum) {
    __shared__ int sm[256];
    int v = (threadIdx.x < NB_SCAN) ? bsum[threadIdx.x] : 0;
    sm[threadIdx.x] = v;
    __syncthreads();
    for (int o = 1; o < 256; o <<= 1) {
        int t = (threadIdx.x >= o) ? sm[threadIdx.x - o] : 0;
        __syncthreads();
        sm[threadIdx.x] += t;
        __syncthreads();
    }
    if (threadIdx.x < NB_SCAN) bsum[threadIdx.x] = sm[threadIdx.x] - v;
}

__global__ void scan3_kernel(const int* __restrict__ deg, const int* __restrict__ incl,
                             const int* __restrict__ bsum, int* __restrict__ rowptr,
                             int* __restrict__ cursor) {
    int i = blockIdx.x * 256 + threadIdx.x;
    if (i >= N_NODES) return;
    int excl = incl[i] - deg[i] + bsum[i >> 8];
    rowptr[i] = excl;
    cursor[i] = excl;
    if (i == N_NODES - 1) rowptr[N_NODES] = excl + deg[i];
}

__global__ void scatter_kernel(const int* __restrict__ ei, int* __restrict__ cursor,
                               int* __restrict__ colsrc) {
    int e = blockIdx.x * blockDim.x + threadIdx.x;
    if (e >= NE) return;
    int s = ei[e], d = ei[NE + e];
    int pos = atomicAdd(&cursor[d], 1);
    colsrc[pos] = s;
}

// ---------------- GEMM (fp32, row-major, C = A[M,K] @ B[K,Nc]) ----------------

#define BM 64
#define BN 64
#define BKK 16

__global__ __launch_bounds__(256) void gemm_f32(const float* __restrict__ A,
                                                const float* __restrict__ B,
                                                float* __restrict__ C,
                                                int M, int K, int Nc) {
    __shared__ float As[BKK][BM + 1];
    __shared__ float Bs[BKK][BN];
    const int t  = threadIdx.x;
    const int tx = t & 15, ty = t >> 4;
    const int row0 = blockIdx.y * BM;
    const int col0 = blockIdx.x * BN;
    float acc[4][4] = {};
    for (int k0 = 0; k0 < K; k0 += BKK) {
#pragma unroll
        for (int i = 0; i < 4; i++) {
            int e = t + i * 256;
            int m = e >> 4, k = e & 15;
            int r = row0 + m;
            As[k][m] = (r < M) ? A[(long)r * K + k0 + k] : 0.f;
        }
#pragma unroll
        for (int i = 0; i < 4; i++) {
            int e = t + i * 256;
            int k = e >> 6, n = e & 63;
            Bs[k][n] = B[(long)(k0 + k) * Nc + col0 + n];
        }
        __syncthreads();
#pragma unroll
        for (int k = 0; k < BKK; k++) {
            float a[4], b[4];
#pragma unroll
            for (int i = 0; i < 4; i++) a[i] = As[k][ty * 4 + i];
#pragma unroll
            for (int j = 0; j < 4; j++) b[j] = Bs[k][tx * 4 + j];
#pragma unroll
            for (int i = 0; i < 4; i++)
#pragma unroll
                for (int j = 0; j < 4; j++) acc[i][j] += a[i] * b[j];
        }
        __syncthreads();
    }
#pragma unroll
    for (int i = 0; i < 4; i++) {
        int r = row0 + ty * 4 + i;
        if (r < M) {
#pragma unroll
            for (int j = 0; j < 4; j++)
                C[(long)r * Nc + col0 + tx * 4 + j] = acc[i][j];
        }
    }
}

// ---------------- per-node alpha (dot with a_src/a_dst) ----------------

__global__ void alpha_kernel(const float* __restrict__ xw,
                             const float* __restrict__ a_src,
                             const float* __restrict__ a_dst,
                             float* __restrict__ as_, float* __restrict__ ad_,
                             int NH, int H, int C) {
    int i = blockIdx.x * blockDim.x + threadIdx.x;
    if (i >= NH) return;
    int n = i / H, h = i - n * H;
    const float* row = xw + (long)n * HC + h * C;
    const float* vs  = a_src + h * C;
    const float* vd  = a_dst + h * C;
    float s = 0.f, d = 0.f;
    for (int k = 0; k < C; k++) {
        float v = row[k];
        s += v * vs[k];
        d += v * vd[k];
    }
    as_[i] = s;
    ad_[i] = d;
}

// ---------------- fused GAT aggregate: one wave per dst node ----------------
// CHUNK = 64/H edges per iteration; lane l handles edge-slot (l % CHUNK) for
// head (l / CHUNK); lane l's channels 2l,2l+1 belong to head l/CHUNK, so
// per-lane scalar softmax state is for exactly the right head.

template<int H>
__global__ __launch_bounds__(256) void gat_agg_kernel(const int* __restrict__ rowptr,
                                                      const int* __restrict__ colsrc,
                                                      const float* __restrict__ as_,
                                                      const float* __restrict__ ad_,
                                                      const float* __restrict__ xw,
                                                      const float* __restrict__ bias,
                                                      float* __restrict__ outbuf,
                                                      int fuse_elu) {
    constexpr int CHUNK = 64 / H;
    int n    = (blockIdx.x * blockDim.x + threadIdx.x) >> 6;
    int lane = threadIdx.x & 63;
    if (n >= N_NODES) return;
    const int c     = lane * 2;
    const int h_my  = lane / CHUNK;
    const int eslot = lane & (CHUNK - 1);
    const int gbase = lane - eslot;

    // self-loop seeds the online softmax: m = e_self, den = exp(0) = 1, acc = xw[n]
    const float adn = ad_[n * H + h_my];
    float m;
    {
        float v = as_[n * H + h_my] + adn;
        m = (v > 0.f) ? v : 0.2f * v;
    }
    float den = 1.f;
    float2 acc = *reinterpret_cast<const float2*>(xw + (long)n * HC + c);

    const int rbeg = rowptr[n], rend = rowptr[n + 1];
    for (int base = rbeg; base < rend; base += CHUNK) {
        int idx = base + eslot;
        int s   = (idx < rend) ? colsrc[idx] : -1;
        float ev;
        if (s >= 0) {
            float v = as_[(long)s * H + h_my] + adn;
            ev = (v > 0.f) ? v : 0.2f * v;
        } else {
            ev = -INFINITY;
        }
        float cm = ev;
#pragma unroll
        for (int o = CHUNK / 2; o > 0; o >>= 1) cm = fmaxf(cm, __shfl_xor(cm, o));
        float nm = fmaxf(m, cm);
        float sc = __expf(m - nm);
        den *= sc;
        acc.x *= sc; acc.y *= sc;
        m = nm;
        float e_ = (s >= 0) ? __expf(ev - nm) : 0.f;
        float ssum = e_;
#pragma unroll
        for (int o = CHUNK / 2; o > 0; o >>= 1) ssum += __shfl_xor(ssum, o);
        den += ssum;
        // gather: serial over chunk edges, lanes over channels.
        // unroll 4 -> 4 outstanding L2/L3 loads per lane (latency-bound loop)
        int cnt = min(CHUNK, rend - base);
#pragma unroll 4
        for (int j = 0; j < cnt; j++) {
            int   sj = __shfl(s, j);            // same for all head groups
            float aj = __shfl(e_, gbase + j);   // edge j's exp for MY head
            const float2 v = *reinterpret_cast<const float2*>(xw + (long)sj * HC + c);
            acc.x += aj * v.x;
            acc.y += aj * v.y;
        }
    }

    float inv = 1.f / (den + 1e-16f);
    float x0 = acc.x * inv, x1 = acc.y * inv;
    if (fuse_elu) {
        x0 += bias[c]; x1 += bias[c + 1];
        x0 = (x0 > 0.f) ? x0 : (__expf(x0) - 1.f);
        x1 = (x1 > 0.f) ? x1 : (__expf(x1) - 1.f);
    }
    float2 o; o.x = x0; o.y = x1;
    *reinterpret_cast<float2*>(outbuf + (long)n * HC + c) = o;
}

// ---------------- final stage (atomic-light) ----------------

// wave per node: ents = elu(out2 + b2) in place; logits[n] = ents.Wq[:128]+qdot+mask
__global__ __launch_bounds__(256) void ents_logits_kernel(float* __restrict__ ents,
                                                          const float* __restrict__ b2,
                                                          const float* __restrict__ Wq,
                                                          const int* __restrict__ qmask,
                                                          const float* __restrict__ scal,
                                                          float* __restrict__ logits) {
    int wid  = (blockIdx.x * blockDim.x + threadIdx.x) >> 6;
    int lane = threadIdx.x & 63;
    if (wid >= N_NODES) return;
    int c = lane * 2;
    float2 v = *reinterpret_cast<float2*>(ents + (long)wid * HC + c);
    float x0 = v.x + b2[c], x1 = v.y + b2[c + 1];
    x0 = (x0 > 0.f) ? x0 : (__expf(x0) - 1.f);
    x1 = (x1 > 0.f) ? x1 : (__expf(x1) - 1.f);
    float2 w; w.x = x0; w.y = x1;
    *reinterpret_cast<float2*>(ents + (long)wid * HC + c) = w;
    float acc = x0 * Wq[c] + x1 * Wq[c + 1];
#pragma unroll
    for (int o = 32; o > 0; o >>= 1) acc += __shfl_down(acc, o);
    if (lane == 0)
        logits[wid] = acc + scal[0] + ((float)qmask[wid] - 1.f) * 1e9f;
}

// grid-stride block max, one atomic per block (196 total)
__global__ __launch_bounds__(256) void red_max_kernel(const float* __restrict__ logits,
                                                      float* scal) {
    __shared__ float sm[256];
    float mx = -INFINITY;
    for (int i = blockIdx.x * 256 + threadIdx.x; i < N_NODES; i += gridDim.x * 256)
        mx = fmaxf(mx, logits[i]);
    sm[threadIdx.x] = mx;
    __syncthreads();
    for (int o = 128; o > 0; o >>= 1) {
        if (threadIdx.x < o) sm[threadIdx.x] = fmaxf(sm[threadIdx.x], sm[threadIdx.x + o]);
        __syncthreads();
    }
    if (threadIdx.x == 0) atomicMaxFloat(&scal[1], sm[0]);
}

// logits <- exp(logits - gmax); one atomicAdd per block (196 total)
__global__ __launch_bounds__(256) void red_sum_kernel(float* __restrict__ logits,
                                                      float* scal) {
    __shared__ float sm[256];
    const float gmax = scal[1];
    float acc = 0.f;
    for (int i = blockIdx.x * 256 + threadIdx.x; i < N_NODES; i += gridDim.x * 256) {
        float ex = __expf(logits[i] - gmax);
        logits[i] = ex;
        acc += ex;
    }
    sm[threadIdx.x] = acc;
    __syncthreads();
    for (int o = 128; o > 0; o >>= 1) {
        if (threadIdx.x < o) sm[threadIdx.x] += sm[threadIdx.x + o];
        __syncthreads();
    }
    if (threadIdx.x == 0) unsafeAtomicAdd(&scal[2], sm[0]);
}

__global__ void attn_kernel(const float* __restrict__ logits, const float* __restrict__ scal,
                            float* __restrict__ attn_out) {
    int n = blockIdx.x * blockDim.x + threadIdx.x;
    if (n >= N_NODES) return;
    attn_out[n] = logits[n] / scal[2];
}

// pooled partials: block b writes partial[b*128+c] (no atomics)
__global__ __launch_bounds__(128) void pooled_partial_kernel(const float* __restrict__ ents,
                                                             const float* __restrict__ attn,
                                                             float* __restrict__ partial) {
    int c = threadIdx.x;
    float acc = 0.f;
    for (int n = blockIdx.x; n < N_NODES; n += gridDim.x)
        acc += attn[n] * ents[(long)n * HC + c];
    partial[(long)blockIdx.x * HC + c] = acc;
}

__global__ __launch_bounds__(128) void pooled_reduce_kernel(const float* __restrict__ partial,
                                                            float* __restrict__ pooled) {
    int c = threadIdx.x;
    float acc = 0.f;
    for (int b = 0; b < NB_POOL; b++) acc += partial[(long)b * HC + c];
    pooled[c] = acc;
}

// ---------------- launch ----------------

extern "C" void kernel_launch(void* const* d_in, const int* in_sizes, int n_in,
                              void* d_out, int out_size, void* d_ws, size_t ws_size,
                              hipStream_t stream) {
    const float* x     = (const float*)d_in[0];
    const int*   ei    = (const int*)d_in[1];
    const float* q     = (const float*)d_in[2];
    const int*   qmask = (const int*)d_in[3];
    const float* W1    = (const float*)d_in[5];
    const float* asrc1 = (const float*)d_in[6];
    const float* adst1 = (const float*)d_in[7];
    const float* b1    = (const float*)d_in[8];
    const float* W2    = (const float*)d_in[9];
    const float* asrc2 = (const float*)d_in[10];
    const float* adst2 = (const float*)d_in[11];
    const float* b2    = (const float*)d_in[12];
    const float* Wq    = (const float*)d_in[13];
    const float* bq    = (const float*)d_in[14];

    float* out    = (float*)d_out;
    float* pooled = out;                              // [128]
    float* ents   = out + HC;                         // [N,128]
    float* attn   = out + HC + (long)N_NODES * HC;    // [N]

    // workspace layout
    float* ws      = (float*)d_ws;
    float* xw      = ws;                              // N*128
    float* as1     = xw + (long)N_NODES * HC;         // N*4
    float* ad1     = as1 + N_NODES * H1;
    float* as2     = ad1 + N_NODES * H1;              // N
    float* ad2     = as2 + N_NODES;
    float* logits  = ad2 + N_NODES;                   // N
    float* scal    = logits + N_NODES;                // 4
    float* partial = scal + 4;                        // NB_POOL*128
    int*   deg     = (int*)(partial + NB_POOL * HC);  // N
    int*   incl    = deg + N_NODES;                   // N
    int*   bsum    = incl + N_NODES;                  // 256
    int*   rowptr  = bsum + 256;                      // N+1
    int*   cursor  = rowptr + N_NODES + 1;            // N
    int*   colsrc  = cursor + N_NODES;                // NE

    const int TB = 256;
    const int g_nh1 = (N_NODES * H1 + TB - 1) / TB;   // 782
    const int g_n   = (N_NODES + TB - 1) / TB;        // 196
    const int g_e   = (NE + TB - 1) / TB;             // 3125
    const int g_nw  = (N_NODES + 3) / 4;              // node-waves, 4/block
    dim3 gemm_grid(HC / BN, (N_NODES + BM - 1) / BM); // (2, 782)

    hipMemsetAsync(deg, 0, N_NODES * sizeof(int), stream);
    init_scal_kernel<<<1, 1, 0, stream>>>(scal);
    qdot_kernel<<<1, TB, 0, stream>>>(q, Wq, bq, scal);

    // ---- CSR build (dst-sorted) ----
    hist_kernel<<<g_e, TB, 0, stream>>>(ei, deg);
    scan1_kernel<<<NB_SCAN, TB, 0, stream>>>(deg, incl, bsum);
    scan2_kernel<<<1, TB, 0, stream>>>(bsum);
    scan3_kernel<<<NB_SCAN, TB, 0, stream>>>(deg, incl, bsum, rowptr, cursor);
    scatter_kernel<<<g_e, TB, 0, stream>>>(ei, cursor, colsrc);

    // ---- layer 1 ----
    gemm_f32<<<gemm_grid, TB, 0, stream>>>(x, W1, xw, N_NODES, F_IN, HC);
    alpha_kernel<<<g_nh1, TB, 0, stream>>>(xw, asrc1, adst1, as1, ad1, N_NODES * H1, H1, C1);
    gat_agg_kernel<H1><<<g_nw, TB, 0, stream>>>(rowptr, colsrc, as1, ad1, xw, b1, ents, 1);

    // ---- layer 2 ----
    gemm_f32<<<gemm_grid, TB, 0, stream>>>(ents, W2, xw, N_NODES, HC, HC);
    alpha_kernel<<<g_n, TB, 0, stream>>>(xw, asrc2, adst2, as2, ad2, N_NODES, 1, C2);
    gat_agg_kernel<1><<<g_nw, TB, 0, stream>>>(rowptr, colsrc, as2, ad2, xw, b2, ents, 0);

    // ---- final ----
    ents_logits_kernel<<<g_nw, TB, 0, stream>>>(ents, b2, Wq, qmask, scal, logits);
    red_max_kernel<<<NB_SCAN, TB, 0, stream>>>(logits, scal);
    red_sum_kernel<<<NB_SCAN, TB, 0, stream>>>(logits, scal);
    attn_kernel<<<g_n, TB, 0, stream>>>(logits, scal, attn);
    pooled_partial_kernel<<<NB_POOL, 128, 0, stream>>>(ents, attn, partial);
    pooled_reduce_kernel<<<1, 128, 0, stream>>>(partial, pooled);
}

// Round 10
// 546.236 us; speedup vs baseline: 4.9421x; 1.0625x over previous
//
#include <hip/hip_runtime.h>
#include <math.h>

#define N_NODES 50000
#define F_IN    256
#define H1      4
#define C1      32
#define HC      128
#define C2      128
#define QDIM    768
#define NE      800000
#define NB_SCAN 196          // ceil(50000/256)
#define NB_POOL 512

// ---------------- helpers ----------------

__device__ __forceinline__ void atomicMaxFloat(float* addr, float val) {
    if (val >= 0.f)
        atomicMax(reinterpret_cast<int*>(addr), __float_as_int(val));
    else
        atomicMin(reinterpret_cast<unsigned int*>(addr), __float_as_uint(val));
}

// ---------------- init ----------------

__global__ void init_scal_kernel(float* scal) {
    scal[1] = -INFINITY;   // global logit max
    scal[2] = 0.f;         // global exp sum
}

// qdot = q . Wq[128:] + bq
__global__ void qdot_kernel(const float* __restrict__ q, const float* __restrict__ Wq,
                            const float* __restrict__ bq, float* scal) {
    __shared__ float sm[256];
    float acc = 0.f;
    for (int i = threadIdx.x; i < QDIM; i += 256) acc += q[i] * Wq[C2 + i];
    sm[threadIdx.x] = acc;
    __syncthreads();
    for (int o = 128; o > 0; o >>= 1) {
        if (threadIdx.x < o) sm[threadIdx.x] += sm[threadIdx.x + o];
        __syncthreads();
    }
    if (threadIdx.x == 0) scal[0] = sm[0] + bq[0];
}

// ---------------- CSR build (counting sort by dst) ----------------

__global__ void hist_kernel(const int* __restrict__ ei, int* __restrict__ deg) {
    int e = blockIdx.x * blockDim.x + threadIdx.x;
    if (e >= NE) return;
    atomicAdd(&deg[ei[NE + e]], 1);
}

__global__ void scan1_kernel(const int* __restrict__ deg, int* __restrict__ incl,
                             int* __restrict__ bsum) {
    __shared__ int sm[256];
    int i = blockIdx.x * 256 + threadIdx.x;
    int v = (i < N_NODES) ? deg[i] : 0;
    sm[threadIdx.x] = v;
    __syncthreads();
    for (int o = 1; o < 256; o <<= 1) {
        int t = (threadIdx.x >= o) ? sm[threadIdx.x - o] : 0;
        __syncthreads();
        sm[threadIdx.x] += t;
        __syncthreads();
    }
    if (i < N_NODES) incl[i] = sm[threadIdx.x];
    if (threadIdx.x == 255) bsum[blockIdx.x] = sm[255];
}

__global__ void scan2_kernel(int* __restrict__ bsum) {
    __shared__ int sm[256];
    int v = (threadIdx.x < NB_SCAN) ? bsum[threadIdx.x] : 0;
    sm[threadIdx.x] = v;
    __syncthreads();
    for (int o = 1; o < 256; o <<= 1) {
        int t = (threadIdx.x >= o) ? sm[threadIdx.x - o] : 0;
        __syncthreads();
        sm[threadIdx.x] += t;
        __syncthreads();
    }
    if (threadIdx.x < NB_SCAN) bsum[threadIdx.x] = sm[threadIdx.x] - v;
}

__global__ void scan3_kernel(const int* __restrict__ deg, const int* __restrict__ incl,
                             const int* __restrict__ bsum, int* __restrict__ rowptr,
                             int* __restrict__ cursor) {
    int i = blockIdx.x * 256 + threadIdx.x;
    if (i >= N_NODES) return;
    int excl = incl[i] - deg[i] + bsum[i >> 8];
    rowptr[i] = excl;
    cursor[i] = excl;
    if (i == N_NODES - 1) rowptr[N_NODES] = excl + deg[i];
}

__global__ void scatter_kernel(const int* __restrict__ ei, int* __restrict__ cursor,
                               int* __restrict__ colsrc) {
    int e = blockIdx.x * blockDim.x + threadIdx.x;
    if (e >= NE) return;
    int s = ei[e], d = ei[NE + e];
    int pos = atomicAdd(&cursor[d], 1);
    colsrc[pos] = s;
}

// ---------------- GEMM (fp32, row-major, C[M,128] = A[M,K] @ B[K,128]) ----------------
// BN = 128 = full output width. 256 threads: ty=t>>4 covers 4 rows each,
// tx=t&15 covers cols {tx*4..+3} and {64+tx*4..+3}. 32 FMA / 3 ds_read_b128.
// As padded to 68 words/row: 16B-aligned vector reads, 2-way (free) write banks.

#define BM 64
#define BN 128
#define BKK 16

__global__ __launch_bounds__(256) void gemm_f32(const float* __restrict__ A,
                                                const float* __restrict__ B,
                                                float* __restrict__ C,
                                                int M, int K) {
    __shared__ float As[BKK][BM + 4];   // [k][m], 68-word rows
    __shared__ float Bs[BKK][BN];
    const int t  = threadIdx.x;
    const int tx = t & 15, ty = t >> 4;
    const int row0 = blockIdx.x * BM;

    // A staging: thread t loads float4 A[row0 + (t>>2)][k0 + (t&3)*4 ..]
    const int ar  = t >> 2;         // 0..63
    const int akb = (t & 3) * 4;    // 0,4,8,12
    // B staging: thread t loads float4 B[k0 + t>>5][(t*4)&127] and k+8 row
    const int bk = t >> 5;          // 0..7
    const int bn = (t * 4) & 127;

    float acc[4][8] = {};

    for (int k0 = 0; k0 < K; k0 += BKK) {
        float4 av = make_float4(0.f, 0.f, 0.f, 0.f);
        if (row0 + ar < M)
            av = *reinterpret_cast<const float4*>(A + (long)(row0 + ar) * K + k0 + akb);
        As[akb + 0][ar] = av.x;
        As[akb + 1][ar] = av.y;
        As[akb + 2][ar] = av.z;
        As[akb + 3][ar] = av.w;
        *reinterpret_cast<float4*>(&Bs[bk][bn]) =
            *reinterpret_cast<const float4*>(B + (long)(k0 + bk) * BN + bn);
        *reinterpret_cast<float4*>(&Bs[bk + 8][bn]) =
            *reinterpret_cast<const float4*>(B + (long)(k0 + bk + 8) * BN + bn);
        __syncthreads();
#pragma unroll
        for (int k = 0; k < BKK; k++) {
            float4 a  = *reinterpret_cast<const float4*>(&As[k][ty * 4]);
            float4 b0 = *reinterpret_cast<const float4*>(&Bs[k][tx * 4]);
            float4 b1 = *reinterpret_cast<const float4*>(&Bs[k][64 + tx * 4]);
            float aa[4] = {a.x, a.y, a.z, a.w};
            float bb[8] = {b0.x, b0.y, b0.z, b0.w, b1.x, b1.y, b1.z, b1.w};
#pragma unroll
            for (int i = 0; i < 4; i++)
#pragma unroll
                for (int j = 0; j < 8; j++) acc[i][j] += aa[i] * bb[j];
        }
        __syncthreads();
    }
#pragma unroll
    for (int i = 0; i < 4; i++) {
        int r = row0 + ty * 4 + i;
        if (r < M) {
            float4 c0 = make_float4(acc[i][0], acc[i][1], acc[i][2], acc[i][3]);
            float4 c1 = make_float4(acc[i][4], acc[i][5], acc[i][6], acc[i][7]);
            *reinterpret_cast<float4*>(C + (long)r * BN + tx * 4)      = c0;
            *reinterpret_cast<float4*>(C + (long)r * BN + 64 + tx * 4) = c1;
        }
    }
}

// ---------------- per-node alpha (dot with a_src/a_dst) ----------------

__global__ void alpha_kernel(const float* __restrict__ xw,
                             const float* __restrict__ a_src,
                             const float* __restrict__ a_dst,
                             float* __restrict__ as_, float* __restrict__ ad_,
                             int NH, int H, int C) {
    int i = blockIdx.x * blockDim.x + threadIdx.x;
    if (i >= NH) return;
    int n = i / H, h = i - n * H;
    const float* row = xw + (long)n * HC + h * C;
    const float* vs  = a_src + h * C;
    const float* vd  = a_dst + h * C;
    float s = 0.f, d = 0.f;
    for (int k = 0; k < C; k++) {
        float v = row[k];
        s += v * vs[k];
        d += v * vd[k];
    }
    as_[i] = s;
    ad_[i] = d;
}

// ---------------- fused GAT aggregate: one wave per dst node ----------------
// CHUNK = 64/H edges per iteration; lane l handles edge-slot (l % CHUNK) for
// head (l / CHUNK); lane l's channels 2l,2l+1 belong to head l/CHUNK, so
// per-lane scalar softmax state is for exactly the right head.

template<int H>
__global__ __launch_bounds__(256) void gat_agg_kernel(const int* __restrict__ rowptr,
                                                      const int* __restrict__ colsrc,
                                                      const float* __restrict__ as_,
                                                      const float* __restrict__ ad_,
                                                      const float* __restrict__ xw,
                                                      const float* __restrict__ bias,
                                                      float* __restrict__ outbuf,
                                                      int fuse_elu) {
    constexpr int CHUNK = 64 / H;
    int n    = (blockIdx.x * blockDim.x + threadIdx.x) >> 6;
    int lane = threadIdx.x & 63;
    if (n >= N_NODES) return;
    const int c     = lane * 2;
    const int h_my  = lane / CHUNK;
    const int eslot = lane & (CHUNK - 1);
    const int gbase = lane - eslot;

    // self-loop seeds the online softmax: m = e_self, den = exp(0) = 1, acc = xw[n]
    const float adn = ad_[n * H + h_my];
    float m;
    {
        float v = as_[n * H + h_my] + adn;
        m = (v > 0.f) ? v : 0.2f * v;
    }
    float den = 1.f;
    float2 acc = *reinterpret_cast<const float2*>(xw + (long)n * HC + c);

    const int rbeg = rowptr[n], rend = rowptr[n + 1];
    for (int base = rbeg; base < rend; base += CHUNK) {
        int idx = base + eslot;
        int s   = (idx < rend) ? colsrc[idx] : -1;
        float ev;
        if (s >= 0) {
            float v = as_[(long)s * H + h_my] + adn;
            ev = (v > 0.f) ? v : 0.2f * v;
        } else {
            ev = -INFINITY;
        }
        float cm = ev;
#pragma unroll
        for (int o = CHUNK / 2; o > 0; o >>= 1) cm = fmaxf(cm, __shfl_xor(cm, o));
        float nm = fmaxf(m, cm);
        float sc = __expf(m - nm);
        den *= sc;
        acc.x *= sc; acc.y *= sc;
        m = nm;
        float e_ = (s >= 0) ? __expf(ev - nm) : 0.f;
        float ssum = e_;
#pragma unroll
        for (int o = CHUNK / 2; o > 0; o >>= 1) ssum += __shfl_xor(ssum, o);
        den += ssum;
        // gather: serial over chunk edges, lanes over channels.
        // unroll 4 -> 4 outstanding L2/L3 loads per lane (latency-bound loop)
        int cnt = min(CHUNK, rend - base);
#pragma unroll 4
        for (int j = 0; j < cnt; j++) {
            int   sj = __shfl(s, j);            // same for all head groups
            float aj = __shfl(e_, gbase + j);   // edge j's exp for MY head
            const float2 v = *reinterpret_cast<const float2*>(xw + (long)sj * HC + c);
            acc.x += aj * v.x;
            acc.y += aj * v.y;
        }
    }

    float inv = 1.f / (den + 1e-16f);
    float x0 = acc.x * inv, x1 = acc.y * inv;
    if (fuse_elu) {
        x0 += bias[c]; x1 += bias[c + 1];
        x0 = (x0 > 0.f) ? x0 : (__expf(x0) - 1.f);
        x1 = (x1 > 0.f) ? x1 : (__expf(x1) - 1.f);
    }
    float2 o; o.x = x0; o.y = x1;
    *reinterpret_cast<float2*>(outbuf + (long)n * HC + c) = o;
}

// ---------------- final stage (atomic-light) ----------------

// wave per node: ents = elu(out2 + b2) in place; logits[n] = ents.Wq[:128]+qdot+mask
__global__ __launch_bounds__(256) void ents_logits_kernel(float* __restrict__ ents,
                                                          const float* __restrict__ b2,
                                                          const float* __restrict__ Wq,
                                                          const int* __restrict__ qmask,
                                                          const float* __restrict__ scal,
                                                          float* __restrict__ logits) {
    int wid  = (blockIdx.x * blockDim.x + threadIdx.x) >> 6;
    int lane = threadIdx.x & 63;
    if (wid >= N_NODES) return;
    int c = lane * 2;
    float2 v = *reinterpret_cast<float2*>(ents + (long)wid * HC + c);
    float x0 = v.x + b2[c], x1 = v.y + b2[c + 1];
    x0 = (x0 > 0.f) ? x0 : (__expf(x0) - 1.f);
    x1 = (x1 > 0.f) ? x1 : (__expf(x1) - 1.f);
    float2 w; w.x = x0; w.y = x1;
    *reinterpret_cast<float2*>(ents + (long)wid * HC + c) = w;
    float acc = x0 * Wq[c] + x1 * Wq[c + 1];
#pragma unroll
    for (int o = 32; o > 0; o >>= 1) acc += __shfl_down(acc, o);
    if (lane == 0)
        logits[wid] = acc + scal[0] + ((float)qmask[wid] - 1.f) * 1e9f;
}

// grid-stride block max, one atomic per block (196 total)
__global__ __launch_bounds__(256) void red_max_kernel(const float* __restrict__ logits,
                                                      float* scal) {
    __shared__ float sm[256];
    float mx = -INFINITY;
    for (int i = blockIdx.x * 256 + threadIdx.x; i < N_NODES; i += gridDim.x * 256)
        mx = fmaxf(mx, logits[i]);
    sm[threadIdx.x] = mx;
    __syncthreads();
    for (int o = 128; o > 0; o >>= 1) {
        if (threadIdx.x < o) sm[threadIdx.x] = fmaxf(sm[threadIdx.x], sm[threadIdx.x + o]);
        __syncthreads();
    }
    if (threadIdx.x == 0) atomicMaxFloat(&scal[1], sm[0]);
}

// logits <- exp(logits - gmax); one atomicAdd per block (196 total)
__global__ __launch_bounds__(256) void red_sum_kernel(float* __restrict__ logits,
                                                      float* scal) {
    __shared__ float sm[256];
    const float gmax = scal[1];
    float acc = 0.f;
    for (int i = blockIdx.x * 256 + threadIdx.x; i < N_NODES; i += gridDim.x * 256) {
        float ex = __expf(logits[i] - gmax);
        logits[i] = ex;
        acc += ex;
    }
    sm[threadIdx.x] = acc;
    __syncthreads();
    for (int o = 128; o > 0; o >>= 1) {
        if (threadIdx.x < o) sm[threadIdx.x] += sm[threadIdx.x + o];
        __syncthreads();
    }
    if (threadIdx.x == 0) unsafeAtomicAdd(&scal[2], sm[0]);
}

__global__ void attn_kernel(const float* __restrict__ logits, const float* __restrict__ scal,
                            float* __restrict__ attn_out) {
    int n = blockIdx.x * blockDim.x + threadIdx.x;
    if (n >= N_NODES) return;
    attn_out[n] = logits[n] / scal[2];
}

// pooled partials: block b writes partial[b*128+c] (no atomics)
__global__ __launch_bounds__(128) void pooled_partial_kernel(const float* __restrict__ ents,
                                                             const float* __restrict__ attn,
                                                             float* __restrict__ partial) {
    int c = threadIdx.x;
    float acc = 0.f;
    for (int n = blockIdx.x; n < N_NODES; n += gridDim.x)
        acc += attn[n] * ents[(long)n * HC + c];
    partial[(long)blockIdx.x * HC + c] = acc;
}

__global__ __launch_bounds__(128) void pooled_reduce_kernel(const float* __restrict__ partial,
                                                            float* __restrict__ pooled) {
    int c = threadIdx.x;
    float acc = 0.f;
    for (int b = 0; b < NB_POOL; b++) acc += partial[(long)b * HC + c];
    pooled[c] = acc;
}

// ---------------- launch ----------------

extern "C" void kernel_launch(void* const* d_in, const int* in_sizes, int n_in,
                              void* d_out, int out_size, void* d_ws, size_t ws_size,
                              hipStream_t stream) {
    const float* x     = (const float*)d_in[0];
    const int*   ei    = (const int*)d_in[1];
    const float* q     = (const float*)d_in[2];
    const int*   qmask = (const int*)d_in[3];
    const float* W1    = (const float*)d_in[5];
    const float* asrc1 = (const float*)d_in[6];
    const float* adst1 = (const float*)d_in[7];
    const float* b1    = (const float*)d_in[8];
    const float* W2    = (const float*)d_in[9];
    const float* asrc2 = (const float*)d_in[10];
    const float* adst2 = (const float*)d_in[11];
    const float* b2    = (const float*)d_in[12];
    const float* Wq    = (const float*)d_in[13];
    const float* bq    = (const float*)d_in[14];

    float* out    = (float*)d_out;
    float* pooled = out;                              // [128]
    float* ents   = out + HC;                         // [N,128]
    float* attn   = out + HC + (long)N_NODES * HC;    // [N]

    // workspace layout
    float* ws      = (float*)d_ws;
    float* xw      = ws;                              // N*128
    float* as1     = xw + (long)N_NODES * HC;         // N*4
    float* ad1     = as1 + N_NODES * H1;
    float* as2     = ad1 + N_NODES * H1;              // N
    float* ad2     = as2 + N_NODES;
    float* logits  = ad2 + N_NODES;                   // N
    float* scal    = logits + N_NODES;                // 4
    float* partial = scal + 4;                        // NB_POOL*128
    int*   deg     = (int*)(partial + NB_POOL * HC);  // N
    int*   incl    = deg + N_NODES;                   // N
    int*   bsum    = incl + N_NODES;                  // 256
    int*   rowptr  = bsum + 256;                      // N+1
    int*   cursor  = rowptr + N_NODES + 1;            // N
    int*   colsrc  = cursor + N_NODES;                // NE

    const int TB = 256;
    const int g_nh1 = (N_NODES * H1 + TB - 1) / TB;   // 782
    const int g_n   = (N_NODES + TB - 1) / TB;        // 196
    const int g_e   = (NE + TB - 1) / TB;             // 3125
    const int g_nw  = (N_NODES + 3) / 4;              // node-waves, 4/block
    const int g_gemm = (N_NODES + BM - 1) / BM;       // 782

    hipMemsetAsync(deg, 0, N_NODES * sizeof(int), stream);
    init_scal_kernel<<<1, 1, 0, stream>>>(scal);
    qdot_kernel<<<1, TB, 0, stream>>>(q, Wq, bq, scal);

    // ---- CSR build (dst-sorted) ----
    hist_kernel<<<g_e, TB, 0, stream>>>(ei, deg);
    scan1_kernel<<<NB_SCAN, TB, 0, stream>>>(deg, incl, bsum);
    scan2_kernel<<<1, TB, 0, stream>>>(bsum);
    scan3_kernel<<<NB_SCAN, TB, 0, stream>>>(deg, incl, bsum, rowptr, cursor);
    scatter_kernel<<<g_e, TB, 0, stream>>>(ei, cursor, colsrc);

    // ---- layer 1 ----
    gemm_f32<<<g_gemm, TB, 0, stream>>>(x, W1, xw, N_NODES, F_IN);
    alpha_kernel<<<g_nh1, TB, 0, stream>>>(xw, asrc1, adst1, as1, ad1, N_NODES * H1, H1, C1);
    gat_agg_kernel<H1><<<g_nw, TB, 0, stream>>>(rowptr, colsrc, as1, ad1, xw, b1, ents, 1);

    // ---- layer 2 ----
    gemm_f32<<<g_gemm, TB, 0, stream>>>(ents, W2, xw, N_NODES, HC);
    alpha_kernel<<<g_n, TB, 0, stream>>>(xw, asrc2, adst2, as2, ad2, N_NODES, 1, C2);
    gat_agg_kernel<1><<<g_nw, TB, 0, stream>>>(rowptr, colsrc, as2, ad2, xw, b2, ents, 0);

    // ---- final ----
    ents_logits_kernel<<<g_nw, TB, 0, stream>>>(ents, b2, Wq, qmask, scal, logits);
    red_max_kernel<<<NB_SCAN, TB, 0, stream>>>(logits, scal);
    red_sum_kernel<<<NB_SCAN, TB, 0, stream>>>(logits, scal);
    attn_kernel<<<g_n, TB, 0, stream>>>(logits, scal, attn);
    pooled_partial_kernel<<<NB_POOL, 128, 0, stream>>>(ents, attn, partial);
    pooled_reduce_kernel<<<1, 128, 0, stream>>>(partial, pooled);
}

// Round 12
// 511.795 us; speedup vs baseline: 5.2747x; 1.0673x over previous
//
#include <hip/hip_runtime.h>
#include <hip/hip_fp16.h>
#include <math.h>

#define N_NODES 50000
#define F_IN    256
#define H1      4
#define C1      32
#define HC      128
#define C2      128
#define QDIM    768
#define NE      800000
#define NB_SCAN 196          // ceil(50000/256)
#define NB_POOL 512

// ---------------- helpers ----------------

__device__ __forceinline__ void atomicMaxFloat(float* addr, float val) {
    if (val >= 0.f)
        atomicMax(reinterpret_cast<int*>(addr), __float_as_int(val));
    else
        atomicMin(reinterpret_cast<unsigned int*>(addr), __float_as_uint(val));
}

// ---------------- init ----------------

__global__ void init_scal_kernel(float* scal) {
    scal[1] = -INFINITY;   // global logit max
    scal[2] = 0.f;         // global exp sum
}

// qdot = q . Wq[128:] + bq
__global__ void qdot_kernel(const float* __restrict__ q, const float* __restrict__ Wq,
                            const float* __restrict__ bq, float* scal) {
    __shared__ float sm[256];
    float acc = 0.f;
    for (int i = threadIdx.x; i < QDIM; i += 256) acc += q[i] * Wq[C2 + i];
    sm[threadIdx.x] = acc;
    __syncthreads();
    for (int o = 128; o > 0; o >>= 1) {
        if (threadIdx.x < o) sm[threadIdx.x] += sm[threadIdx.x + o];
        __syncthreads();
    }
    if (threadIdx.x == 0) scal[0] = sm[0] + bq[0];
}

// ---------------- CSR build (counting sort by dst) ----------------

__global__ void hist_kernel(const int* __restrict__ ei, int* __restrict__ deg) {
    int e = blockIdx.x * blockDim.x + threadIdx.x;
    if (e >= NE) return;
    atomicAdd(&deg[ei[NE + e]], 1);
}

__global__ void scan1_kernel(const int* __restrict__ deg, int* __restrict__ incl,
                             int* __restrict__ bsum) {
    __shared__ int sm[256];
    int i = blockIdx.x * 256 + threadIdx.x;
    int v = (i < N_NODES) ? deg[i] : 0;
    sm[threadIdx.x] = v;
    __syncthreads();
    for (int o = 1; o < 256; o <<= 1) {
        int t = (threadIdx.x >= o) ? sm[threadIdx.x - o] : 0;
        __syncthreads();
        sm[threadIdx.x] += t;
        __syncthreads();
    }
    if (i < N_NODES) incl[i] = sm[threadIdx.x];
    if (threadIdx.x == 255) bsum[blockIdx.x] = sm[255];
}

__global__ void scan2_kernel(int* __restrict__ bsum) {
    __shared__ int sm[256];
    int v = (threadIdx.x < NB_SCAN) ? bsum[threadIdx.x] : 0;
    sm[threadIdx.x] = v;
    __syncthreads();
    for (int o = 1; o < 256; o <<= 1) {
        int t = (threadIdx.x >= o) ? sm[threadIdx.x - o] : 0;
        __syncthreads();
        sm[threadIdx.x] += t;
        __syncthreads();
    }
    if (threadIdx.x < NB_SCAN) bsum[threadIdx.x] = sm[threadIdx.x] - v;
}

__global__ void scan3_kernel(const int* __restrict__ deg, const int* __restrict__ incl,
                             const int* __restrict__ bsum, int* __restrict__ rowptr,
                             int* __restrict__ cursor) {
    int i = blockIdx.x * 256 + threadIdx.x;
    if (i >= N_NODES) return;
    int excl = incl[i] - deg[i] + bsum[i >> 8];
    rowptr[i] = excl;
    cursor[i] = excl;
    if (i == N_NODES - 1) rowptr[N_NODES] = excl + deg[i];
}

__global__ void scatter_kernel(const int* __restrict__ ei, int* __restrict__ cursor,
                               int* __restrict__ colsrc) {
    int e = blockIdx.x * blockDim.x + threadIdx.x;
    if (e >= NE) return;
    int s = ei[e], d = ei[NE + e];
    int pos = atomicAdd(&cursor[d], 1);
    colsrc[pos] = s;
}

// ---------------- GEMM (fp32 in, fp16 out; C[M,128] = A[M,K] @ B[K,128]) ----------------
// BN = 128 = full output width. 256 threads: ty covers 4 rows, tx covers 8 cols
// (two float4 groups). Output written as fp16 (only consumers: alpha + gather).

#define BM 64
#define BN 128
#define BKK 16

__global__ __launch_bounds__(256) void gemm_f32(const float* __restrict__ A,
                                                const float* __restrict__ B,
                                                __half* __restrict__ Ch,
                                                int M, int K) {
    __shared__ float As[BKK][BM + 4];   // [k][m], 68-word rows
    __shared__ float Bs[BKK][BN];
    const int t  = threadIdx.x;
    const int tx = t & 15, ty = t >> 4;
    const int row0 = blockIdx.x * BM;

    const int ar  = t >> 2;         // 0..63
    const int akb = (t & 3) * 4;    // 0,4,8,12
    const int bk = t >> 5;          // 0..7
    const int bn = (t * 4) & 127;

    float acc[4][8] = {};

    for (int k0 = 0; k0 < K; k0 += BKK) {
        float4 av = make_float4(0.f, 0.f, 0.f, 0.f);
        if (row0 + ar < M)
            av = *reinterpret_cast<const float4*>(A + (long)(row0 + ar) * K + k0 + akb);
        As[akb + 0][ar] = av.x;
        As[akb + 1][ar] = av.y;
        As[akb + 2][ar] = av.z;
        As[akb + 3][ar] = av.w;
        *reinterpret_cast<float4*>(&Bs[bk][bn]) =
            *reinterpret_cast<const float4*>(B + (long)(k0 + bk) * BN + bn);
        *reinterpret_cast<float4*>(&Bs[bk + 8][bn]) =
            *reinterpret_cast<const float4*>(B + (long)(k0 + bk + 8) * BN + bn);
        __syncthreads();
#pragma unroll
        for (int k = 0; k < BKK; k++) {
            float4 a  = *reinterpret_cast<const float4*>(&As[k][ty * 4]);
            float4 b0 = *reinterpret_cast<const float4*>(&Bs[k][tx * 4]);
            float4 b1 = *reinterpret_cast<const float4*>(&Bs[k][64 + tx * 4]);
            float aa[4] = {a.x, a.y, a.z, a.w};
            float bb[8] = {b0.x, b0.y, b0.z, b0.w, b1.x, b1.y, b1.z, b1.w};
#pragma unroll
            for (int i = 0; i < 4; i++)
#pragma unroll
                for (int j = 0; j < 8; j++) acc[i][j] += aa[i] * bb[j];
        }
        __syncthreads();
    }
#pragma unroll
    for (int i = 0; i < 4; i++) {
        int r = row0 + ty * 4 + i;
        if (r < M) {
            union { __half2 h2[2]; uint2 u; } p0, p1;
            p0.h2[0] = __floats2half2_rn(acc[i][0], acc[i][1]);
            p0.h2[1] = __floats2half2_rn(acc[i][2], acc[i][3]);
            p1.h2[0] = __floats2half2_rn(acc[i][4], acc[i][5]);
            p1.h2[1] = __floats2half2_rn(acc[i][6], acc[i][7]);
            *reinterpret_cast<uint2*>(Ch + (long)r * BN + tx * 4)      = p0.u;
            *reinterpret_cast<uint2*>(Ch + (long)r * BN + 64 + tx * 4) = p1.u;
        }
    }
}

// ---------------- per-node alpha (dot with a_src/a_dst), fp16 xw ----------------

__global__ void alpha_kernel(const __half* __restrict__ xw,
                             const float* __restrict__ a_src,
                             const float* __restrict__ a_dst,
                             float* __restrict__ as_, float* __restrict__ ad_,
                             int NH, int H, int C) {
    int i = blockIdx.x * blockDim.x + threadIdx.x;
    if (i >= NH) return;
    int n = i / H, h = i - n * H;
    const __half2* row = reinterpret_cast<const __half2*>(xw + (long)n * HC + h * C);
    const float* vs  = a_src + h * C;
    const float* vd  = a_dst + h * C;
    float s = 0.f, d = 0.f;
    for (int k2 = 0; k2 < C / 2; k2++) {
        float2 f = __half22float2(row[k2]);
        s += f.x * vs[2 * k2] + f.y * vs[2 * k2 + 1];
        d += f.x * vd[2 * k2] + f.y * vd[2 * k2 + 1];
    }
    as_[i] = s;
    ad_[i] = d;
}

// ---------------- fused GAT aggregate: one wave per dst node ----------------
// CHUNK = 64/H edges per iteration; lane l handles edge-slot (l % CHUNK) for
// head (l / CHUNK); lane l's channels 2l,2l+1 belong to head l/CHUNK, so
// per-lane scalar softmax state is for exactly the right head.
// xw gathered in fp16 (256 B/edge instead of 512 B — fetch-bound kernel).

template<int H>
__global__ __launch_bounds__(256) void gat_agg_kernel(const int* __restrict__ rowptr,
                                                      const int* __restrict__ colsrc,
                                                      const float* __restrict__ as_,
                                                      const float* __restrict__ ad_,
                                                      const __half* __restrict__ xw,
                                                      const float* __restrict__ bias,
                                                      float* __restrict__ outbuf,
                                                      int fuse_elu) {
    constexpr int CHUNK = 64 / H;
    int n    = (blockIdx.x * blockDim.x + threadIdx.x) >> 6;
    int lane = threadIdx.x & 63;
    if (n >= N_NODES) return;
    const int c     = lane * 2;
    const int h_my  = lane / CHUNK;
    const int eslot = lane & (CHUNK - 1);
    const int gbase = lane - eslot;

    // self-loop seeds the online softmax: m = e_self, den = exp(0) = 1, acc = xw[n]
    const float adn = ad_[n * H + h_my];
    float m;
    {
        float v = as_[n * H + h_my] + adn;
        m = (v > 0.f) ? v : 0.2f * v;
    }
    float den = 1.f;
    float2 acc = __half22float2(*reinterpret_cast<const __half2*>(xw + (long)n * HC + c));

    const int rbeg = rowptr[n], rend = rowptr[n + 1];
    for (int base = rbeg; base < rend; base += CHUNK) {
        int idx = base + eslot;
        int s   = (idx < rend) ? colsrc[idx] : -1;
        float ev;
        if (s >= 0) {
            float v = as_[(long)s * H + h_my] + adn;
            ev = (v > 0.f) ? v : 0.2f * v;
        } else {
            ev = -INFINITY;
        }
        float cm = ev;
#pragma unroll
        for (int o = CHUNK / 2; o > 0; o >>= 1) cm = fmaxf(cm, __shfl_xor(cm, o));
        float nm = fmaxf(m, cm);
        float sc = __expf(m - nm);
        den *= sc;
        acc.x *= sc; acc.y *= sc;
        m = nm;
        float e_ = (s >= 0) ? __expf(ev - nm) : 0.f;
        float ssum = e_;
#pragma unroll
        for (int o = CHUNK / 2; o > 0; o >>= 1) ssum += __shfl_xor(ssum, o);
        den += ssum;
        // gather: serial over chunk edges, lanes over channels.
        // unroll 4 -> 4 outstanding loads per lane (latency/fetch-bound loop)
        int cnt = min(CHUNK, rend - base);
#pragma unroll 4
        for (int j = 0; j < cnt; j++) {
            int   sj = __shfl(s, j);            // same for all head groups
            float aj = __shfl(e_, gbase + j);   // edge j's exp for MY head
            const float2 v =
                __half22float2(*reinterpret_cast<const __half2*>(xw + (long)sj * HC + c));
            acc.x += aj * v.x;
            acc.y += aj * v.y;
        }
    }

    float inv = 1.f / (den + 1e-16f);
    float x0 = acc.x * inv, x1 = acc.y * inv;
    if (fuse_elu) {
        x0 += bias[c]; x1 += bias[c + 1];
        x0 = (x0 > 0.f) ? x0 : (__expf(x0) - 1.f);
        x1 = (x1 > 0.f) ? x1 : (__expf(x1) - 1.f);
    }
    float2 o; o.x = x0; o.y = x1;
    *reinterpret_cast<float2*>(outbuf + (long)n * HC + c) = o;
}

// ---------------- final stage (atomic-light) ----------------

// wave per node: ents = elu(out2 + b2) in place; logits[n] = ents.Wq[:128]+qdot+mask
__global__ __launch_bounds__(256) void ents_logits_kernel(float* __restrict__ ents,
                                                          const float* __restrict__ b2,
                                                          const float* __restrict__ Wq,
                                                          const int* __restrict__ qmask,
                                                          const float* __restrict__ scal,
                                                          float* __restrict__ logits) {
    int wid  = (blockIdx.x * blockDim.x + threadIdx.x) >> 6;
    int lane = threadIdx.x & 63;
    if (wid >= N_NODES) return;
    int c = lane * 2;
    float2 v = *reinterpret_cast<float2*>(ents + (long)wid * HC + c);
    float x0 = v.x + b2[c], x1 = v.y + b2[c + 1];
    x0 = (x0 > 0.f) ? x0 : (__expf(x0) - 1.f);
    x1 = (x1 > 0.f) ? x1 : (__expf(x1) - 1.f);
    float2 w; w.x = x0; w.y = x1;
    *reinterpret_cast<float2*>(ents + (long)wid * HC + c) = w;
    float acc = x0 * Wq[c] + x1 * Wq[c + 1];
#pragma unroll
    for (int o = 32; o > 0; o >>= 1) acc += __shfl_down(acc, o);
    if (lane == 0)
        logits[wid] = acc + scal[0] + ((float)qmask[wid] - 1.f) * 1e9f;
}

// grid-stride block max, one atomic per block (196 total)
__global__ __launch_bounds__(256) void red_max_kernel(const float* __restrict__ logits,
                                                      float* scal) {
    __shared__ float sm[256];
    float mx = -INFINITY;
    for (int i = blockIdx.x * 256 + threadIdx.x; i < N_NODES; i += gridDim.x * 256)
        mx = fmaxf(mx, logits[i]);
    sm[threadIdx.x] = mx;
    __syncthreads();
    for (int o = 128; o > 0; o >>= 1) {
        if (threadIdx.x < o) sm[threadIdx.x] = fmaxf(sm[threadIdx.x], sm[threadIdx.x + o]);
        __syncthreads();
    }
    if (threadIdx.x == 0) atomicMaxFloat(&scal[1], sm[0]);
}

// logits <- exp(logits - gmax); one atomicAdd per block (196 total)
__global__ __launch_bounds__(256) void red_sum_kernel(float* __restrict__ logits,
                                                      float* scal) {
    __shared__ float sm[256];
    const float gmax = scal[1];
    float acc = 0.f;
    for (int i = blockIdx.x * 256 + threadIdx.x; i < N_NODES; i += gridDim.x * 256) {
        float ex = __expf(logits[i] - gmax);
        logits[i] = ex;
        acc += ex;
    }
    sm[threadIdx.x] = acc;
    __syncthreads();
    for (int o = 128; o > 0; o >>= 1) {
        if (threadIdx.x < o) sm[threadIdx.x] += sm[threadIdx.x + o];
        __syncthreads();
    }
    if (threadIdx.x == 0) unsafeAtomicAdd(&scal[2], sm[0]);
}

__global__ void attn_kernel(const float* __restrict__ logits, const float* __restrict__ scal,
                            float* __restrict__ attn_out) {
    int n = blockIdx.x * blockDim.x + threadIdx.x;
    if (n >= N_NODES) return;
    attn_out[n] = logits[n] / scal[2];
}

// pooled partials: block b writes partial[b*128+c] (no atomics)
__global__ __launch_bounds__(128) void pooled_partial_kernel(const float* __restrict__ ents,
                                                             const float* __restrict__ attn,
                                                             float* __restrict__ partial) {
    int c = threadIdx.x;
    float acc = 0.f;
    for (int n = blockIdx.x; n < N_NODES; n += gridDim.x)
        acc += attn[n] * ents[(long)n * HC + c];
    partial[(long)blockIdx.x * HC + c] = acc;
}

__global__ __launch_bounds__(128) void pooled_reduce_kernel(const float* __restrict__ partial,
                                                            float* __restrict__ pooled) {
    int c = threadIdx.x;
    float acc = 0.f;
    for (int b = 0; b < NB_POOL; b++) acc += partial[(long)b * HC + c];
    pooled[c] = acc;
}

// ---------------- launch ----------------

extern "C" void kernel_launch(void* const* d_in, const int* in_sizes, int n_in,
                              void* d_out, int out_size, void* d_ws, size_t ws_size,
                              hipStream_t stream) {
    const float* x     = (const float*)d_in[0];
    const int*   ei    = (const int*)d_in[1];
    const float* q     = (const float*)d_in[2];
    const int*   qmask = (const int*)d_in[3];
    const float* W1    = (const float*)d_in[5];
    const float* asrc1 = (const float*)d_in[6];
    const float* adst1 = (const float*)d_in[7];
    const float* b1    = (const float*)d_in[8];
    const float* W2    = (const float*)d_in[9];
    const float* asrc2 = (const float*)d_in[10];
    const float* adst2 = (const float*)d_in[11];
    const float* b2    = (const float*)d_in[12];
    const float* Wq    = (const float*)d_in[13];
    const float* bq    = (const float*)d_in[14];

    float* out    = (float*)d_out;
    float* pooled = out;                              // [128]
    float* ents   = out + HC;                         // [N,128]
    float* attn   = out + HC + (long)N_NODES * HC;    // [N]

    // workspace layout (xw is fp16: N*128 halves == N*64 floats)
    float*  ws     = (float*)d_ws;
    __half* xw     = (__half*)ws;                     // N*128 halves (12.8 MB)
    float* as1     = ws + (long)N_NODES * HC / 2;     // N*4
    float* ad1     = as1 + N_NODES * H1;
    float* as2     = ad1 + N_NODES * H1;              // N
    float* ad2     = as2 + N_NODES;
    float* logits  = ad2 + N_NODES;                   // N
    float* scal    = logits + N_NODES;                // 4
    float* partial = scal + 4;                        // NB_POOL*128
    int*   deg     = (int*)(partial + NB_POOL * HC);  // N
    int*   incl    = deg + N_NODES;                   // N
    int*   bsum    = incl + N_NODES;                  // 256
    int*   rowptr  = bsum + 256;                      // N+1
    int*   cursor  = rowptr + N_NODES + 1;            // N
    int*   colsrc  = cursor + N_NODES;                // NE

    const int TB = 256;
    const int g_nh1 = (N_NODES * H1 + TB - 1) / TB;   // 782
    const int g_n   = (N_NODES + TB - 1) / TB;        // 196
    const int g_e   = (NE + TB - 1) / TB;             // 3125
    const int g_nw  = (N_NODES + 3) / 4;              // node-waves, 4/block
    const int g_gemm = (N_NODES + BM - 1) / BM;       // 782

    hipMemsetAsync(deg, 0, N_NODES * sizeof(int), stream);
    init_scal_kernel<<<1, 1, 0, stream>>>(scal);
    qdot_kernel<<<1, TB, 0, stream>>>(q, Wq, bq, scal);

    // ---- CSR build (dst-sorted) ----
    hist_kernel<<<g_e, TB, 0, stream>>>(ei, deg);
    scan1_kernel<<<NB_SCAN, TB, 0, stream>>>(deg, incl, bsum);
    scan2_kernel<<<1, TB, 0, stream>>>(bsum);
    scan3_kernel<<<NB_SCAN, TB, 0, stream>>>(deg, incl, bsum, rowptr, cursor);
    scatter_kernel<<<g_e, TB, 0, stream>>>(ei, cursor, colsrc);

    // ---- layer 1 ----
    gemm_f32<<<g_gemm, TB, 0, stream>>>(x, W1, xw, N_NODES, F_IN);
    alpha_kernel<<<g_nh1, TB, 0, stream>>>(xw, asrc1, adst1, as1, ad1, N_NODES * H1, H1, C1);
    gat_agg_kernel<H1><<<g_nw, TB, 0, stream>>>(rowptr, colsrc, as1, ad1, xw, b1, ents, 1);

    // ---- layer 2 ----
    gemm_f32<<<g_gemm, TB, 0, stream>>>(ents, W2, xw, N_NODES, HC);
    alpha_kernel<<<g_n, TB, 0, stream>>>(xw, asrc2, adst2, as2, ad2, N_NODES, 1, C2);
    gat_agg_kernel<1><<<g_nw, TB, 0, stream>>>(rowptr, colsrc, as2, ad2, xw, b2, ents, 0);

    // ---- final ----
    ents_logits_kernel<<<g_nw, TB, 0, stream>>>(ents, b2, Wq, qmask, scal, logits);
    red_max_kernel<<<NB_SCAN, TB, 0, stream>>>(logits, scal);
    red_sum_kernel<<<NB_SCAN, TB, 0, stream>>>(logits, scal);
    attn_kernel<<<g_n, TB, 0, stream>>>(logits, scal, attn);
    pooled_partial_kernel<<<NB_POOL, 128, 0, stream>>>(ents, attn, partial);
    pooled_reduce_kernel<<<1, 128, 0, stream>>>(partial, pooled);
}

// Round 13
// 482.399 us; speedup vs baseline: 5.5961x; 1.0609x over previous
//
#include <hip/hip_runtime.h>
#include <hip/hip_fp16.h>
#include <math.h>

#define N_NODES 50000
#define F_IN    256
#define H1      4
#define C1      32
#define HC      128
#define C2      128
#define QDIM    768
#define NE      800000
#define NB_SCAN 196          // ceil(50000/256)
#define NB_POOL 512

// ---------------- helpers ----------------

__device__ __forceinline__ void atomicMaxFloat(float* addr, float val) {
    if (val >= 0.f)
        atomicMax(reinterpret_cast<int*>(addr), __float_as_int(val));
    else
        atomicMin(reinterpret_cast<unsigned int*>(addr), __float_as_uint(val));
}

// ---------------- init ----------------

__global__ void init_scal_kernel(float* scal) {
    scal[1] = -INFINITY;   // global logit max
    scal[2] = 0.f;         // global exp sum
}

// qdot = q . Wq[128:] + bq
__global__ void qdot_kernel(const float* __restrict__ q, const float* __restrict__ Wq,
                            const float* __restrict__ bq, float* scal) {
    __shared__ float sm[256];
    float acc = 0.f;
    for (int i = threadIdx.x; i < QDIM; i += 256) acc += q[i] * Wq[C2 + i];
    sm[threadIdx.x] = acc;
    __syncthreads();
    for (int o = 128; o > 0; o >>= 1) {
        if (threadIdx.x < o) sm[threadIdx.x] += sm[threadIdx.x + o];
        __syncthreads();
    }
    if (threadIdx.x == 0) scal[0] = sm[0] + bq[0];
}

// ---------------- CSR build (counting sort by dst) ----------------

__global__ void hist_kernel(const int* __restrict__ ei, int* __restrict__ deg) {
    int e = blockIdx.x * blockDim.x + threadIdx.x;
    if (e >= NE) return;
    atomicAdd(&deg[ei[NE + e]], 1);
}

__global__ void scan1_kernel(const int* __restrict__ deg, int* __restrict__ incl,
                             int* __restrict__ bsum) {
    __shared__ int sm[256];
    int i = blockIdx.x * 256 + threadIdx.x;
    int v = (i < N_NODES) ? deg[i] : 0;
    sm[threadIdx.x] = v;
    __syncthreads();
    for (int o = 1; o < 256; o <<= 1) {
        int t = (threadIdx.x >= o) ? sm[threadIdx.x - o] : 0;
        __syncthreads();
        sm[threadIdx.x] += t;
        __syncthreads();
    }
    if (i < N_NODES) incl[i] = sm[threadIdx.x];
    if (threadIdx.x == 255) bsum[blockIdx.x] = sm[255];
}

__global__ void scan2_kernel(int* __restrict__ bsum) {
    __shared__ int sm[256];
    int v = (threadIdx.x < NB_SCAN) ? bsum[threadIdx.x] : 0;
    sm[threadIdx.x] = v;
    __syncthreads();
    for (int o = 1; o < 256; o <<= 1) {
        int t = (threadIdx.x >= o) ? sm[threadIdx.x - o] : 0;
        __syncthreads();
        sm[threadIdx.x] += t;
        __syncthreads();
    }
    if (threadIdx.x < NB_SCAN) bsum[threadIdx.x] = sm[threadIdx.x] - v;
}

__global__ void scan3_kernel(const int* __restrict__ deg, const int* __restrict__ incl,
                             const int* __restrict__ bsum, int* __restrict__ rowptr,
                             int* __restrict__ cursor) {
    int i = blockIdx.x * 256 + threadIdx.x;
    if (i >= N_NODES) return;
    int excl = incl[i] - deg[i] + bsum[i >> 8];
    rowptr[i] = excl;
    cursor[i] = excl;
    if (i == N_NODES - 1) rowptr[N_NODES] = excl + deg[i];
}

__global__ void scatter_kernel(const int* __restrict__ ei, int* __restrict__ cursor,
                               int* __restrict__ colsrc) {
    int e = blockIdx.x * blockDim.x + threadIdx.x;
    if (e >= NE) return;
    int s = ei[e], d = ei[NE + e];
    int pos = atomicAdd(&cursor[d], 1);
    colsrc[pos] = s;
}

// ---------------- GEMM (fp32 in, fp16 out; C[M,128] = A[M,K] @ B[K,128]) ----------------

#define BM 64
#define BN 128
#define BKK 16

__global__ __launch_bounds__(256) void gemm_f32(const float* __restrict__ A,
                                                const float* __restrict__ B,
                                                __half* __restrict__ Ch,
                                                int M, int K) {
    __shared__ float As[BKK][BM + 4];   // [k][m], 68-word rows
    __shared__ float Bs[BKK][BN];
    const int t  = threadIdx.x;
    const int tx = t & 15, ty = t >> 4;
    const int row0 = blockIdx.x * BM;

    const int ar  = t >> 2;         // 0..63
    const int akb = (t & 3) * 4;    // 0,4,8,12
    const int bk = t >> 5;          // 0..7
    const int bn = (t * 4) & 127;

    float acc[4][8] = {};

    for (int k0 = 0; k0 < K; k0 += BKK) {
        float4 av = make_float4(0.f, 0.f, 0.f, 0.f);
        if (row0 + ar < M)
            av = *reinterpret_cast<const float4*>(A + (long)(row0 + ar) * K + k0 + akb);
        As[akb + 0][ar] = av.x;
        As[akb + 1][ar] = av.y;
        As[akb + 2][ar] = av.z;
        As[akb + 3][ar] = av.w;
        *reinterpret_cast<float4*>(&Bs[bk][bn]) =
            *reinterpret_cast<const float4*>(B + (long)(k0 + bk) * BN + bn);
        *reinterpret_cast<float4*>(&Bs[bk + 8][bn]) =
            *reinterpret_cast<const float4*>(B + (long)(k0 + bk + 8) * BN + bn);
        __syncthreads();
#pragma unroll
        for (int k = 0; k < BKK; k++) {
            float4 a  = *reinterpret_cast<const float4*>(&As[k][ty * 4]);
            float4 b0 = *reinterpret_cast<const float4*>(&Bs[k][tx * 4]);
            float4 b1 = *reinterpret_cast<const float4*>(&Bs[k][64 + tx * 4]);
            float aa[4] = {a.x, a.y, a.z, a.w};
            float bb[8] = {b0.x, b0.y, b0.z, b0.w, b1.x, b1.y, b1.z, b1.w};
#pragma unroll
            for (int i = 0; i < 4; i++)
#pragma unroll
                for (int j = 0; j < 8; j++) acc[i][j] += aa[i] * bb[j];
        }
        __syncthreads();
    }
#pragma unroll
    for (int i = 0; i < 4; i++) {
        int r = row0 + ty * 4 + i;
        if (r < M) {
            union { __half2 h2[2]; uint2 u; } p0, p1;
            p0.h2[0] = __floats2half2_rn(acc[i][0], acc[i][1]);
            p0.h2[1] = __floats2half2_rn(acc[i][2], acc[i][3]);
            p1.h2[0] = __floats2half2_rn(acc[i][4], acc[i][5]);
            p1.h2[1] = __floats2half2_rn(acc[i][6], acc[i][7]);
            *reinterpret_cast<uint2*>(Ch + (long)r * BN + tx * 4)      = p0.u;
            *reinterpret_cast<uint2*>(Ch + (long)r * BN + 64 + tx * 4) = p1.u;
        }
    }
}

// ---------------- per-node alpha (dot with a_src/a_dst), fp16 xw ----------------

__global__ void alpha_kernel(const __half* __restrict__ xw,
                             const float* __restrict__ a_src,
                             const float* __restrict__ a_dst,
                             float* __restrict__ as_, float* __restrict__ ad_,
                             int NH, int H, int C) {
    int i = blockIdx.x * blockDim.x + threadIdx.x;
    if (i >= NH) return;
    int n = i / H, h = i - n * H;
    const __half2* row = reinterpret_cast<const __half2*>(xw + (long)n * HC + h * C);
    const float* vs  = a_src + h * C;
    const float* vd  = a_dst + h * C;
    float s = 0.f, d = 0.f;
    for (int k2 = 0; k2 < C / 2; k2++) {
        float2 f = __half22float2(row[k2]);
        s += f.x * vs[2 * k2] + f.y * vs[2 * k2 + 1];
        d += f.x * vd[2 * k2] + f.y * vd[2 * k2 + 1];
    }
    as_[i] = s;
    ad_[i] = d;
}

// ---------------- fused GAT aggregate: one wave per dst node ----------------
// e-phase (unchanged): CHUNK = 64/H edges/iter; lane = h_my*CHUNK + eslot holds
// the exp value of (edge eslot, head h_my); softmax state is per-lane scalar.
// gather (restructured for MLP): wave splits into 4 edge-groups x 16 lanes;
// lane covers 8 fp16 channels (one uint4 = 16B load), so 4 edges are in
// flight per step (16 with unroll 4) instead of 1. Group partials merge via
// shfl_xor(16|32); lanes 0..15 write the row.

template<int H>
__global__ __launch_bounds__(256) void gat_agg_kernel(const int* __restrict__ rowptr,
                                                      const int* __restrict__ colsrc,
                                                      const float* __restrict__ as_,
                                                      const float* __restrict__ ad_,
                                                      const __half* __restrict__ xw,
                                                      const float* __restrict__ bias,
                                                      float* __restrict__ outbuf,
                                                      int fuse_elu) {
    constexpr int CHUNK = 64 / H;
    int n    = (blockIdx.x * blockDim.x + threadIdx.x) >> 6;
    int lane = threadIdx.x & 63;
    if (n >= N_NODES) return;
    // e-phase decomposition
    const int h_my  = lane / CHUNK;
    const int eslot = lane & (CHUNK - 1);
    // gather decomposition
    const int l16   = lane & 15;
    const int grp   = lane >> 4;          // edge-group 0..3
    const int cbase = l16 * 8;            // 8 channels per lane
    const int hg    = (H == 1) ? 0 : (cbase >> 5);   // head of gather channels

    // self-loop seeds the online softmax: m = e_self, den = exp(0) = 1
    const float adn = ad_[n * H + h_my];
    float m;
    {
        float v = as_[n * H + h_my] + adn;
        m = (v > 0.f) ? v : 0.2f * v;
    }
    float den = 1.f;

    // acc: 8 channels fp32; self-loop xw[n] counted once (group 0 only)
    float acc[8] = {};
    if (grp == 0) {
        union { uint4 u; __half2 h[4]; } cv;
        cv.u = *reinterpret_cast<const uint4*>(xw + (long)n * HC + cbase);
#pragma unroll
        for (int k = 0; k < 4; k++) {
            float2 f = __half22float2(cv.h[k]);
            acc[2 * k]     = f.x;
            acc[2 * k + 1] = f.y;
        }
    }

    const int rbeg = rowptr[n], rend = rowptr[n + 1];
    for (int base = rbeg; base < rend; base += CHUNK) {
        int idx = base + eslot;
        int s   = (idx < rend) ? colsrc[idx] : -1;
        float ev;
        if (s >= 0) {
            float v = as_[(long)s * H + h_my] + adn;
            ev = (v > 0.f) ? v : 0.2f * v;
        } else {
            ev = -INFINITY;
        }
        float cm = ev;
#pragma unroll
        for (int o = CHUNK / 2; o > 0; o >>= 1) cm = fmaxf(cm, __shfl_xor(cm, o));
        float nm = fmaxf(m, cm);
        float sc = __expf(m - nm);
        den *= sc;
        m = nm;
        float e_ = (s >= 0) ? __expf(ev - nm) : 0.f;
        float ssum = e_;
#pragma unroll
        for (int o = CHUNK / 2; o > 0; o >>= 1) ssum += __shfl_xor(ssum, o);
        den += ssum;
        // rescale acc by the gather-head's sc (uniform within a head group)
        float sc_g = (H == 1) ? sc : __shfl(sc, hg * CHUNK);
#pragma unroll
        for (int k = 0; k < 8; k++) acc[k] *= sc_g;
        // gather: 4 edges per step (one per group), 16B fp16 loads
        int cnt = min(CHUNK, rend - base);
#pragma unroll 4
        for (int j4 = 0; j4 < cnt; j4 += 4) {
            int eidx = j4 + grp;                       // < CHUNK always
            int   sj = __shfl(s,  eidx);               // lane eidx (head 0) holds s
            float aj = __shfl(e_, hg * CHUNK + eidx);  // exp for MY gather head
            int  sjc = (sj < 0) ? 0 : sj;              // tail edges: aj == 0
            union { uint4 u; __half2 h[4]; } cv;
            cv.u = *reinterpret_cast<const uint4*>(xw + (long)sjc * HC + cbase);
#pragma unroll
            for (int k = 0; k < 4; k++) {
                float2 f = __half22float2(cv.h[k]);
                acc[2 * k]     += aj * f.x;
                acc[2 * k + 1] += aj * f.y;
            }
        }
    }

    // merge the 4 edge-groups
#pragma unroll
    for (int k = 0; k < 8; k++) {
        acc[k] += __shfl_xor(acc[k], 16);
        acc[k] += __shfl_xor(acc[k], 32);
    }
    float den_g = (H == 1) ? den : __shfl(den, hg * CHUNK);
    if (grp == 0) {
        float inv = 1.f / (den_g + 1e-16f);
        float o[8];
#pragma unroll
        for (int k = 0; k < 8; k++) {
            float v = acc[k] * inv;
            if (fuse_elu) {
                v += bias[cbase + k];
                v = (v > 0.f) ? v : (__expf(v) - 1.f);
            }
            o[k] = v;
        }
        float4 o0 = make_float4(o[0], o[1], o[2], o[3]);
        float4 o1 = make_float4(o[4], o[5], o[6], o[7]);
        *reinterpret_cast<float4*>(outbuf + (long)n * HC + cbase)     = o0;
        *reinterpret_cast<float4*>(outbuf + (long)n * HC + cbase + 4) = o1;
    }
}

// ---------------- final stage (atomic-light) ----------------

// wave per node: ents = elu(out2 + b2) in place; logits[n] = ents.Wq[:128]+qdot+mask
__global__ __launch_bounds__(256) void ents_logits_kernel(float* __restrict__ ents,
                                                          const float* __restrict__ b2,
                                                          const float* __restrict__ Wq,
                                                          const int* __restrict__ qmask,
                                                          const float* __restrict__ scal,
                                                          float* __restrict__ logits) {
    int wid  = (blockIdx.x * blockDim.x + threadIdx.x) >> 6;
    int lane = threadIdx.x & 63;
    if (wid >= N_NODES) return;
    int c = lane * 2;
    float2 v = *reinterpret_cast<float2*>(ents + (long)wid * HC + c);
    float x0 = v.x + b2[c], x1 = v.y + b2[c + 1];
    x0 = (x0 > 0.f) ? x0 : (__expf(x0) - 1.f);
    x1 = (x1 > 0.f) ? x1 : (__expf(x1) - 1.f);
    float2 w; w.x = x0; w.y = x1;
    *reinterpret_cast<float2*>(ents + (long)wid * HC + c) = w;
    float acc = x0 * Wq[c] + x1 * Wq[c + 1];
#pragma unroll
    for (int o = 32; o > 0; o >>= 1) acc += __shfl_down(acc, o);
    if (lane == 0)
        logits[wid] = acc + scal[0] + ((float)qmask[wid] - 1.f) * 1e9f;
}

// grid-stride block max, one atomic per block (196 total)
__global__ __launch_bounds__(256) void red_max_kernel(const float* __restrict__ logits,
                                                      float* scal) {
    __shared__ float sm[256];
    float mx = -INFINITY;
    for (int i = blockIdx.x * 256 + threadIdx.x; i < N_NODES; i += gridDim.x * 256)
        mx = fmaxf(mx, logits[i]);
    sm[threadIdx.x] = mx;
    __syncthreads();
    for (int o = 128; o > 0; o >>= 1) {
        if (threadIdx.x < o) sm[threadIdx.x] = fmaxf(sm[threadIdx.x], sm[threadIdx.x + o]);
        __syncthreads();
    }
    if (threadIdx.x == 0) atomicMaxFloat(&scal[1], sm[0]);
}

// logits <- exp(logits - gmax); one atomicAdd per block (196 total)
__global__ __launch_bounds__(256) void red_sum_kernel(float* __restrict__ logits,
                                                      float* scal) {
    __shared__ float sm[256];
    const float gmax = scal[1];
    float acc = 0.f;
    for (int i = blockIdx.x * 256 + threadIdx.x; i < N_NODES; i += gridDim.x * 256) {
        float ex = __expf(logits[i] - gmax);
        logits[i] = ex;
        acc += ex;
    }
    sm[threadIdx.x] = acc;
    __syncthreads();
    for (int o = 128; o > 0; o >>= 1) {
        if (threadIdx.x < o) sm[threadIdx.x] += sm[threadIdx.x + o];
        __syncthreads();
    }
    if (threadIdx.x == 0) unsafeAtomicAdd(&scal[2], sm[0]);
}

__global__ void attn_kernel(const float* __restrict__ logits, const float* __restrict__ scal,
                            float* __restrict__ attn_out) {
    int n = blockIdx.x * blockDim.x + threadIdx.x;
    if (n >= N_NODES) return;
    attn_out[n] = logits[n] / scal[2];
}

// pooled partials: block b writes partial[b*128+c] (no atomics)
__global__ __launch_bounds__(128) void pooled_partial_kernel(const float* __restrict__ ents,
                                                             const float* __restrict__ attn,
                                                             float* __restrict__ partial) {
    int c = threadIdx.x;
    float acc = 0.f;
    for (int n = blockIdx.x; n < N_NODES; n += gridDim.x)
        acc += attn[n] * ents[(long)n * HC + c];
    partial[(long)blockIdx.x * HC + c] = acc;
}

__global__ __launch_bounds__(128) void pooled_reduce_kernel(const float* __restrict__ partial,
                                                            float* __restrict__ pooled) {
    int c = threadIdx.x;
    float acc = 0.f;
    for (int b = 0; b < NB_POOL; b++) acc += partial[(long)b * HC + c];
    pooled[c] = acc;
}

// ---------------- launch ----------------

extern "C" void kernel_launch(void* const* d_in, const int* in_sizes, int n_in,
                              void* d_out, int out_size, void* d_ws, size_t ws_size,
                              hipStream_t stream) {
    const float* x     = (const float*)d_in[0];
    const int*   ei    = (const int*)d_in[1];
    const float* q     = (const float*)d_in[2];
    const int*   qmask = (const int*)d_in[3];
    const float* W1    = (const float*)d_in[5];
    const float* asrc1 = (const float*)d_in[6];
    const float* adst1 = (const float*)d_in[7];
    const float* b1    = (const float*)d_in[8];
    const float* W2    = (const float*)d_in[9];
    const float* asrc2 = (const float*)d_in[10];
    const float* adst2 = (const float*)d_in[11];
    const float* b2    = (const float*)d_in[12];
    const float* Wq    = (const float*)d_in[13];
    const float* bq    = (const float*)d_in[14];

    float* out    = (float*)d_out;
    float* pooled = out;                              // [128]
    float* ents   = out + HC;                         // [N,128]
    float* attn   = out + HC + (long)N_NODES * HC;    // [N]

    // workspace layout (xw is fp16: N*128 halves == N*64 floats)
    float*  ws     = (float*)d_ws;
    __half* xw     = (__half*)ws;                     // N*128 halves (12.8 MB)
    float* as1     = ws + (long)N_NODES * HC / 2;     // N*4
    float* ad1     = as1 + N_NODES * H1;
    float* as2     = ad1 + N_NODES * H1;              // N
    float* ad2     = as2 + N_NODES;
    float* logits  = ad2 + N_NODES;                   // N
    float* scal    = logits + N_NODES;                // 4
    float* partial = scal + 4;                        // NB_POOL*128
    int*   deg     = (int*)(partial + NB_POOL * HC);  // N
    int*   incl    = deg + N_NODES;                   // N
    int*   bsum    = incl + N_NODES;                  // 256
    int*   rowptr  = bsum + 256;                      // N+1
    int*   cursor  = rowptr + N_NODES + 1;            // N
    int*   colsrc  = cursor + N_NODES;                // NE

    const int TB = 256;
    const int g_nh1 = (N_NODES * H1 + TB - 1) / TB;   // 782
    const int g_n   = (N_NODES + TB - 1) / TB;        // 196
    const int g_e   = (NE + TB - 1) / TB;             // 3125
    const int g_nw  = (N_NODES + 3) / 4;              // node-waves, 4/block
    const int g_gemm = (N_NODES + BM - 1) / BM;       // 782

    hipMemsetAsync(deg, 0, N_NODES * sizeof(int), stream);
    init_scal_kernel<<<1, 1, 0, stream>>>(scal);
    qdot_kernel<<<1, TB, 0, stream>>>(q, Wq, bq, scal);

    // ---- CSR build (dst-sorted) ----
    hist_kernel<<<g_e, TB, 0, stream>>>(ei, deg);
    scan1_kernel<<<NB_SCAN, TB, 0, stream>>>(deg, incl, bsum);
    scan2_kernel<<<1, TB, 0, stream>>>(bsum);
    scan3_kernel<<<NB_SCAN, TB, 0, stream>>>(deg, incl, bsum, rowptr, cursor);
    scatter_kernel<<<g_e, TB, 0, stream>>>(ei, cursor, colsrc);

    // ---- layer 1 ----
    gemm_f32<<<g_gemm, TB, 0, stream>>>(x, W1, xw, N_NODES, F_IN);
    alpha_kernel<<<g_nh1, TB, 0, stream>>>(xw, asrc1, adst1, as1, ad1, N_NODES * H1, H1, C1);
    gat_agg_kernel<H1><<<g_nw, TB, 0, stream>>>(rowptr, colsrc, as1, ad1, xw, b1, ents, 1);

    // ---- layer 2 ----
    gemm_f32<<<g_gemm, TB, 0, stream>>>(ents, W2, xw, N_NODES, HC);
    alpha_kernel<<<g_n, TB, 0, stream>>>(xw, asrc2, adst2, as2, ad2, N_NODES, 1, C2);
    gat_agg_kernel<1><<<g_nw, TB, 0, stream>>>(rowptr, colsrc, as2, ad2, xw, b2, ents, 0);

    // ---- final ----
    ents_logits_kernel<<<g_nw, TB, 0, stream>>>(ents, b2, Wq, qmask, scal, logits);
    red_max_kernel<<<NB_SCAN, TB, 0, stream>>>(logits, scal);
    red_sum_kernel<<<NB_SCAN, TB, 0, stream>>>(logits, scal);
    attn_kernel<<<g_n, TB, 0, stream>>>(logits, scal, attn);
    pooled_partial_kernel<<<NB_POOL, 128, 0, stream>>>(ents, attn, partial);
    pooled_reduce_kernel<<<1, 128, 0, stream>>>(partial, pooled);
}

// Round 16
// 467.784 us; speedup vs baseline: 5.7709x; 1.0312x over previous
//
#include <hip/hip_runtime.h>
#include <hip/hip_fp16.h>
#include <math.h>

#define N_NODES 50000
#define F_IN    256
#define H1      4
#define C1      32
#define HC      128
#define C2      128
#define QDIM    768
#define NE      800000
#define NB_SCAN 196          // ceil(50000/256)
#define NB_POOL 512
#define NXCD    8
#define DST_RANGE ((N_NODES + NXCD - 1) / NXCD)   // 6250

// ---------------- helpers ----------------

__device__ __forceinline__ void atomicMaxFloat(float* addr, float val) {
    if (val >= 0.f)
        atomicMax(reinterpret_cast<int*>(addr), __float_as_int(val));
    else
        atomicMin(reinterpret_cast<unsigned int*>(addr), __float_as_uint(val));
}

// ---------------- init ----------------

__global__ void init_scal_kernel(float* scal) {
    scal[1] = -INFINITY;   // global logit max
    scal[2] = 0.f;         // global exp sum
}

// qdot = q . Wq[128:] + bq
__global__ void qdot_kernel(const float* __restrict__ q, const float* __restrict__ Wq,
                            const float* __restrict__ bq, float* scal) {
    __shared__ float sm[256];
    float acc = 0.f;
    for (int i = threadIdx.x; i < QDIM; i += 256) acc += q[i] * Wq[C2 + i];
    sm[threadIdx.x] = acc;
    __syncthreads();
    for (int o = 128; o > 0; o >>= 1) {
        if (threadIdx.x < o) sm[threadIdx.x] += sm[threadIdx.x + o];
        __syncthreads();
    }
    if (threadIdx.x == 0) scal[0] = sm[0] + bq[0];
}

// ---------------- CSR build (counting sort by dst) ----------------

__global__ void hist_kernel(const int* __restrict__ ei, int* __restrict__ deg) {
    int e = blockIdx.x * blockDim.x + threadIdx.x;
    if (e >= NE) return;
    atomicAdd(&deg[ei[NE + e]], 1);
}

__global__ void scan1_kernel(const int* __restrict__ deg, int* __restrict__ incl,
                             int* __restrict__ bsum) {
    __shared__ int sm[256];
    int i = blockIdx.x * 256 + threadIdx.x;
    int v = (i < N_NODES) ? deg[i] : 0;
    sm[threadIdx.x] = v;
    __syncthreads();
    for (int o = 1; o < 256; o <<= 1) {
        int t = (threadIdx.x >= o) ? sm[threadIdx.x - o] : 0;
        __syncthreads();
        sm[threadIdx.x] += t;
        __syncthreads();
    }
    if (i < N_NODES) incl[i] = sm[threadIdx.x];
    if (threadIdx.x == 255) bsum[blockIdx.x] = sm[255];
}

__global__ void scan2_kernel(int* __restrict__ bsum) {
    __shared__ int sm[256];
    int v = (threadIdx.x < NB_SCAN) ? bsum[threadIdx.x] : 0;
    sm[threadIdx.x] = v;
    __syncthreads();
    for (int o = 1; o < 256; o <<= 1) {
        int t = (threadIdx.x >= o) ? sm[threadIdx.x - o] : 0;
        __syncthreads();
        sm[threadIdx.x] += t;
        __syncthreads();
    }
    if (threadIdx.x < NB_SCAN) bsum[threadIdx.x] = sm[threadIdx.x] - v;
}

__global__ void scan3_kernel(const int* __restrict__ deg, const int* __restrict__ incl,
                             const int* __restrict__ bsum, int* __restrict__ rowptr,
                             int* __restrict__ cursor) {
    int i = blockIdx.x * 256 + threadIdx.x;
    if (i >= N_NODES) return;
    int excl = incl[i] - deg[i] + bsum[i >> 8];
    rowptr[i] = excl;
    cursor[i] = excl;
    if (i == N_NODES - 1) rowptr[N_NODES] = excl + deg[i];
}

// XCD-partitioned scatter: block handles dst-range (bid & 7); consecutive
// blockIdx round-robin across XCDs, so each colsrc line is written from ONE
// XCD -> no cross-XCD dirty-line ping-pong (round-13: WRITE_SIZE was 64B/edge).
// Heuristic only: wrong mapping costs bandwidth, never correctness.
__global__ void scatter_kernel(const int* __restrict__ ei, int* __restrict__ cursor,
                               int* __restrict__ colsrc) {
    const int range = blockIdx.x & (NXCD - 1);
    const int lo = range * DST_RANGE, hi = lo + DST_RANGE;
    const int nb = gridDim.x >> 3;               // slices per range
    const int slice = blockIdx.x >> 3;
    for (int e = slice * blockDim.x + threadIdx.x; e < NE; e += nb * blockDim.x) {
        int d = ei[NE + e];
        if (d >= lo && d < hi) {
            int pos = atomicAdd(&cursor[d], 1);
            colsrc[pos] = ei[e];
        }
    }
}

// ---------------- GEMM (fp32 in, fp16 out; C[M,128] = A[M,K] @ B[K,128]) ----------------
// Software-pipelined: prefetch tile k+1 into registers during tile-k compute
// (round-13: 20.8% occupancy -> TLP can't hide HBM latency; ILP must).

#define BM 64
#define BN 128
#define BKK 16

__global__ __launch_bounds__(256) void gemm_f32(const float* __restrict__ A,
                                                const float* __restrict__ B,
                                                __half* __restrict__ Ch,
                                                int M, int K) {
    __shared__ float As[BKK][BM + 4];   // [k][m], 68-word rows
    __shared__ float Bs[BKK][BN];
    const int t  = threadIdx.x;
    const int tx = t & 15, ty = t >> 4;
    const int row0 = blockIdx.x * BM;

    const int ar  = t >> 2;         // 0..63
    const int akb = (t & 3) * 4;    // 0,4,8,12
    const int bk = t >> 5;          // 0..7
    const int bn = (t * 4) & 127;
    const bool arow_ok = (row0 + ar < M);

    float acc[4][8] = {};

    // prologue: stage tile 0 in registers
    float4 av = make_float4(0.f, 0.f, 0.f, 0.f);
    if (arow_ok)
        av = *reinterpret_cast<const float4*>(A + (long)(row0 + ar) * K + akb);
    float4 bv0 = *reinterpret_cast<const float4*>(B + (long)bk * BN + bn);
    float4 bv1 = *reinterpret_cast<const float4*>(B + (long)(bk + 8) * BN + bn);

    for (int k0 = 0; k0 < K; k0 += BKK) {
        // commit staged tile to LDS
        As[akb + 0][ar] = av.x;
        As[akb + 1][ar] = av.y;
        As[akb + 2][ar] = av.z;
        As[akb + 3][ar] = av.w;
        *reinterpret_cast<float4*>(&Bs[bk][bn]) = bv0;
        *reinterpret_cast<float4*>(&Bs[bk + 8][bn]) = bv1;
        __syncthreads();
        // prefetch next tile (loads complete under the FMA phase)
        if (k0 + BKK < K) {
            if (arow_ok)
                av = *reinterpret_cast<const float4*>(A + (long)(row0 + ar) * K + k0 + BKK + akb);
            bv0 = *reinterpret_cast<const float4*>(B + (long)(k0 + BKK + bk) * BN + bn);
            bv1 = *reinterpret_cast<const float4*>(B + (long)(k0 + BKK + bk + 8) * BN + bn);
        }
#pragma unroll
        for (int k = 0; k < BKK; k++) {
            float4 a  = *reinterpret_cast<const float4*>(&As[k][ty * 4]);
            float4 b0 = *reinterpret_cast<const float4*>(&Bs[k][tx * 4]);
            float4 b1 = *reinterpret_cast<const float4*>(&Bs[k][64 + tx * 4]);
            float aa[4] = {a.x, a.y, a.z, a.w};
            float bb[8] = {b0.x, b0.y, b0.z, b0.w, b1.x, b1.y, b1.z, b1.w};
#pragma unroll
            for (int i = 0; i < 4; i++)
#pragma unroll
                for (int j = 0; j < 8; j++) acc[i][j] += aa[i] * bb[j];
        }
        __syncthreads();
    }
#pragma unroll
    for (int i = 0; i < 4; i++) {
        int r = row0 + ty * 4 + i;
        if (r < M) {
            union { __half2 h2[2]; uint2 u; } p0, p1;
            p0.h2[0] = __floats2half2_rn(acc[i][0], acc[i][1]);
            p0.h2[1] = __floats2half2_rn(acc[i][2], acc[i][3]);
            p1.h2[0] = __floats2half2_rn(acc[i][4], acc[i][5]);
            p1.h2[1] = __floats2half2_rn(acc[i][6], acc[i][7]);
            *reinterpret_cast<uint2*>(Ch + (long)r * BN + tx * 4)      = p0.u;
            *reinterpret_cast<uint2*>(Ch + (long)r * BN + 64 + tx * 4) = p1.u;
        }
    }
}

// ---------------- per-node alpha (dot with a_src/a_dst), fp16 xw ----------------

__global__ void alpha_kernel(const __half* __restrict__ xw,
                             const float* __restrict__ a_src,
                             const float* __restrict__ a_dst,
                             float* __restrict__ as_, float* __restrict__ ad_,
                             int NH, int H, int C) {
    int i = blockIdx.x * blockDim.x + threadIdx.x;
    if (i >= NH) return;
    int n = i / H, h = i - n * H;
    const __half2* row = reinterpret_cast<const __half2*>(xw + (long)n * HC + h * C);
    const float* vs  = a_src + h * C;
    const float* vd  = a_dst + h * C;
    float s = 0.f, d = 0.f;
    for (int k2 = 0; k2 < C / 2; k2++) {
        float2 f = __half22float2(row[k2]);
        s += f.x * vs[2 * k2] + f.y * vs[2 * k2 + 1];
        d += f.x * vd[2 * k2] + f.y * vd[2 * k2 + 1];
    }
    as_[i] = s;
    ad_[i] = d;
}

// ---------------- fused GAT aggregate: one wave per dst node ----------------
// e-phase: CHUNK = 64/H edges/iter; lane = h_my*CHUNK + eslot holds the exp
// value of (edge eslot, head h_my). gather: 4 edge-groups x 16 lanes, lane
// covers 8 fp16 channels (uint4 load) -> 4 edges in flight per step.

template<int H>
__global__ __launch_bounds__(256) void gat_agg_kernel(const int* __restrict__ rowptr,
                                                      const int* __restrict__ colsrc,
                                                      const float* __restrict__ as_,
                                                      const float* __restrict__ ad_,
                                                      const __half* __restrict__ xw,
                                                      const float* __restrict__ bias,
                                                      float* __restrict__ outbuf,
                                                      int fuse_elu) {
    constexpr int CHUNK = 64 / H;
    int n    = (blockIdx.x * blockDim.x + threadIdx.x) >> 6;
    int lane = threadIdx.x & 63;
    if (n >= N_NODES) return;
    const int h_my  = lane / CHUNK;
    const int eslot = lane & (CHUNK - 1);
    const int l16   = lane & 15;
    const int grp   = lane >> 4;          // edge-group 0..3
    const int cbase = l16 * 8;            // 8 channels per lane
    const int hg    = (H == 1) ? 0 : (cbase >> 5);   // head of gather channels

    const float adn = ad_[n * H + h_my];
    float m;
    {
        float v = as_[n * H + h_my] + adn;
        m = (v > 0.f) ? v : 0.2f * v;
    }
    float den = 1.f;

    float acc[8] = {};
    if (grp == 0) {
        union { uint4 u; __half2 h[4]; } cv;
        cv.u = *reinterpret_cast<const uint4*>(xw + (long)n * HC + cbase);
#pragma unroll
        for (int k = 0; k < 4; k++) {
            float2 f = __half22float2(cv.h[k]);
            acc[2 * k]     = f.x;
            acc[2 * k + 1] = f.y;
        }
    }

    const int rbeg = rowptr[n], rend = rowptr[n + 1];
    for (int base = rbeg; base < rend; base += CHUNK) {
        int idx = base + eslot;
        int s   = (idx < rend) ? colsrc[idx] : -1;
        float ev;
        if (s >= 0) {
            float v = as_[(long)s * H + h_my] + adn;
            ev = (v > 0.f) ? v : 0.2f * v;
        } else {
            ev = -INFINITY;
        }
        float cm = ev;
#pragma unroll
        for (int o = CHUNK / 2; o > 0; o >>= 1) cm = fmaxf(cm, __shfl_xor(cm, o));
        float nm = fmaxf(m, cm);
        float sc = __expf(m - nm);
        den *= sc;
        m = nm;
        float e_ = (s >= 0) ? __expf(ev - nm) : 0.f;
        float ssum = e_;
#pragma unroll
        for (int o = CHUNK / 2; o > 0; o >>= 1) ssum += __shfl_xor(ssum, o);
        den += ssum;
        float sc_g = (H == 1) ? sc : __shfl(sc, hg * CHUNK);
#pragma unroll
        for (int k = 0; k < 8; k++) acc[k] *= sc_g;
        int cnt = min(CHUNK, rend - base);
#pragma unroll 4
        for (int j4 = 0; j4 < cnt; j4 += 4) {
            int eidx = j4 + grp;
            int   sj = __shfl(s,  eidx);
            float aj = __shfl(e_, hg * CHUNK + eidx);
            int  sjc = (sj < 0) ? 0 : sj;              // tail edges: aj == 0
            union { uint4 u; __half2 h[4]; } cv;
            cv.u = *reinterpret_cast<const uint4*>(xw + (long)sjc * HC + cbase);
#pragma unroll
            for (int k = 0; k < 4; k++) {
                float2 f = __half22float2(cv.h[k]);
                acc[2 * k]     += aj * f.x;
                acc[2 * k + 1] += aj * f.y;
            }
        }
    }

#pragma unroll
    for (int k = 0; k < 8; k++) {
        acc[k] += __shfl_xor(acc[k], 16);
        acc[k] += __shfl_xor(acc[k], 32);
    }
    float den_g = (H == 1) ? den : __shfl(den, hg * CHUNK);
    if (grp == 0) {
        float inv = 1.f / (den_g + 1e-16f);
        float o[8];
#pragma unroll
        for (int k = 0; k < 8; k++) {
            float v = acc[k] * inv;
            if (fuse_elu) {
                v += bias[cbase + k];
                v = (v > 0.f) ? v : (__expf(v) - 1.f);
            }
            o[k] = v;
        }
        float4 o0 = make_float4(o[0], o[1], o[2], o[3]);
        float4 o1 = make_float4(o[4], o[5], o[6], o[7]);
        *reinterpret_cast<float4*>(outbuf + (long)n * HC + cbase)     = o0;
        *reinterpret_cast<float4*>(outbuf + (long)n * HC + cbase + 4) = o1;
    }
}

// ---------------- final stage (atomic-light) ----------------

__global__ __launch_bounds__(256) void ents_logits_kernel(float* __restrict__ ents,
                                                          const float* __restrict__ b2,
                                                          const float* __restrict__ Wq,
                                                          const int* __restrict__ qmask,
                                                          const float* __restrict__ scal,
                                                          float* __restrict__ logits) {
    int wid  = (blockIdx.x * blockDim.x + threadIdx.x) >> 6;
    int lane = threadIdx.x & 63;
    if (wid >= N_NODES) return;
    int c = lane * 2;
    float2 v = *reinterpret_cast<float2*>(ents + (long)wid * HC + c);
    float x0 = v.x + b2[c], x1 = v.y + b2[c + 1];
    x0 = (x0 > 0.f) ? x0 : (__expf(x0) - 1.f);
    x1 = (x1 > 0.f) ? x1 : (__expf(x1) - 1.f);
    float2 w; w.x = x0; w.y = x1;
    *reinterpret_cast<float2*>(ents + (long)wid * HC + c) = w;
    float acc = x0 * Wq[c] + x1 * Wq[c + 1];
#pragma unroll
    for (int o = 32; o > 0; o >>= 1) acc += __shfl_down(acc, o);
    if (lane == 0)
        logits[wid] = acc + scal[0] + ((float)qmask[wid] - 1.f) * 1e9f;
}

__global__ __launch_bounds__(256) void red_max_kernel(const float* __restrict__ logits,
                                                      float* scal) {
    __shared__ float sm[256];
    float mx = -INFINITY;
    for (int i = blockIdx.x * 256 + threadIdx.x; i < N_NODES; i += gridDim.x * 256)
        mx = fmaxf(mx, logits[i]);
    sm[threadIdx.x] = mx;
    __syncthreads();
    for (int o = 128; o > 0; o >>= 1) {
        if (threadIdx.x < o) sm[threadIdx.x] = fmaxf(sm[threadIdx.x], sm[threadIdx.x + o]);
        __syncthreads();
    }
    if (threadIdx.x == 0) atomicMaxFloat(&scal[1], sm[0]);
}

__global__ __launch_bounds__(256) void red_sum_kernel(float* __restrict__ logits,
                                                      float* scal) {
    __shared__ float sm[256];
    const float gmax = scal[1];
    float acc = 0.f;
    for (int i = blockIdx.x * 256 + threadIdx.x; i < N_NODES; i += gridDim.x * 256) {
        float ex = __expf(logits[i] - gmax);
        logits[i] = ex;
        acc += ex;
    }
    sm[threadIdx.x] = acc;
    __syncthreads();
    for (int o = 128; o > 0; o >>= 1) {
        if (threadIdx.x < o) sm[threadIdx.x] += sm[threadIdx.x + o];
        __syncthreads();
    }
    if (threadIdx.x == 0) unsafeAtomicAdd(&scal[2], sm[0]);
}

__global__ void attn_kernel(const float* __restrict__ logits, const float* __restrict__ scal,
                            float* __restrict__ attn_out) {
    int n = blockIdx.x * blockDim.x + threadIdx.x;
    if (n >= N_NODES) return;
    attn_out[n] = logits[n] / scal[2];
}

__global__ __launch_bounds__(128) void pooled_partial_kernel(const float* __restrict__ ents,
                                                             const float* __restrict__ attn,
                                                             float* __restrict__ partial) {
    int c = threadIdx.x;
    float acc = 0.f;
    for (int n = blockIdx.x; n < N_NODES; n += gridDim.x)
        acc += attn[n] * ents[(long)n * HC + c];
    partial[(long)blockIdx.x * HC + c] = acc;
}

__global__ __launch_bounds__(128) void pooled_reduce_kernel(const float* __restrict__ partial,
                                                            float* __restrict__ pooled) {
    int c = threadIdx.x;
    float acc = 0.f;
    for (int b = 0; b < NB_POOL; b++) acc += partial[(long)b * HC + c];
    pooled[c] = acc;
}

// ---------------- launch ----------------

extern "C" void kernel_launch(void* const* d_in, const int* in_sizes, int n_in,
                              void* d_out, int out_size, void* d_ws, size_t ws_size,
                              hipStream_t stream) {
    const float* x     = (const float*)d_in[0];
    const int*   ei    = (const int*)d_in[1];
    const float* q     = (const float*)d_in[2];
    const int*   qmask = (const int*)d_in[3];
    const float* W1    = (const float*)d_in[5];
    const float* asrc1 = (const float*)d_in[6];
    const float* adst1 = (const float*)d_in[7];
    const float* b1    = (const float*)d_in[8];
    const float* W2    = (const float*)d_in[9];
    const float* asrc2 = (const float*)d_in[10];
    const float* adst2 = (const float*)d_in[11];
    const float* b2    = (const float*)d_in[12];
    const float* Wq    = (const float*)d_in[13];
    const float* bq    = (const float*)d_in[14];

    float* out    = (float*)d_out;
    float* pooled = out;                              // [128]
    float* ents   = out + HC;                         // [N,128]
    float* attn   = out + HC + (long)N_NODES * HC;    // [N]

    // workspace layout (xw is fp16: N*128 halves == N*64 floats)
    float*  ws     = (float*)d_ws;
    __half* xw     = (__half*)ws;                     // N*128 halves (12.8 MB)
    float* as1     = ws + (long)N_NODES * HC / 2;     // N*4
    float* ad1     = as1 + N_NODES * H1;
    float* as2     = ad1 + N_NODES * H1;              // N
    float* ad2     = as2 + N_NODES;
    float* logits  = ad2 + N_NODES;                   // N
    float* scal    = logits + N_NODES;                // 4
    float* partial = scal + 4;                        // NB_POOL*128
    int*   deg     = (int*)(partial + NB_POOL * HC);  // N
    int*   incl    = deg + N_NODES;                   // N
    int*   bsum    = incl + N_NODES;                  // 256
    int*   rowptr  = bsum + 256;                      // N+1
    int*   cursor  = rowptr + N_NODES + 1;            // N
    int*   colsrc  = cursor + N_NODES;                // NE

    const int TB = 256;
    const int g_nh1 = (N_NODES * H1 + TB - 1) / TB;   // 782
    const int g_n   = (N_NODES + TB - 1) / TB;        // 196
    const int g_e   = (NE + TB - 1) / TB;             // 3125
    const int g_nw  = (N_NODES + 3) / 4;              // node-waves, 4/block
    const int g_gemm = (N_NODES + BM - 1) / BM;       // 782
    const int g_scat = 2048;                          // 8 ranges x 256 slices

    hipMemsetAsync(deg, 0, N_NODES * sizeof(int), stream);
    init_scal_kernel<<<1, 1, 0, stream>>>(scal);
    qdot_kernel<<<1, TB, 0, stream>>>(q, Wq, bq, scal);

    // ---- CSR build (dst-sorted) ----
    hist_kernel<<<g_e, TB, 0, stream>>>(ei, deg);
    scan1_kernel<<<NB_SCAN, TB, 0, stream>>>(deg, incl, bsum);
    scan2_kernel<<<1, TB, 0, stream>>>(bsum);
    scan3_kernel<<<NB_SCAN, TB, 0, stream>>>(deg, incl, bsum, rowptr, cursor);
    scatter_kernel<<<g_scat, TB, 0, stream>>>(ei, cursor, colsrc);

    // ---- layer 1 ----
    gemm_f32<<<g_gemm, TB, 0, stream>>>(x, W1, xw, N_NODES, F_IN);
    alpha_kernel<<<g_nh1, TB, 0, stream>>>(xw, asrc1, adst1, as1, ad1, N_NODES * H1, H1, C1);
    gat_agg_kernel<H1><<<g_nw, TB, 0, stream>>>(rowptr, colsrc, as1, ad1, xw, b1, ents, 1);

    // ---- layer 2 ----
    gemm_f32<<<g_gemm, TB, 0, stream>>>(ents, W2, xw, N_NODES, HC);
    alpha_kernel<<<g_n, TB, 0, stream>>>(xw, asrc2, adst2, as2, ad2, N_NODES, 1, C2);
    gat_agg_kernel<1><<<g_nw, TB, 0, stream>>>(rowptr, colsrc, as2, ad2, xw, b2, ents, 0);

    // ---- final ----
    ents_logits_kernel<<<g_nw, TB, 0, stream>>>(ents, b2, Wq, qmask, scal, logits);
    red_max_kernel<<<NB_SCAN, TB, 0, stream>>>(logits, scal);
    red_sum_kernel<<<NB_SCAN, TB, 0, stream>>>(logits, scal);
    attn_kernel<<<g_n, TB, 0, stream>>>(logits, scal, attn);
    pooled_partial_kernel<<<NB_POOL, 128, 0, stream>>>(ents, attn, partial);
    pooled_reduce_kernel<<<1, 128, 0, stream>>>(partial, pooled);
}